// Round 8
// baseline (409.079 us; speedup 1.0000x reference)
//
#include <hip/hip_runtime.h>

typedef __attribute__((ext_vector_type(8))) __bf16 bf16x8;
typedef __attribute__((ext_vector_type(4))) float f32x4;

#define EXP2 __builtin_amdgcn_exp2f
#define LOG2E 1.44269504f

__device__ __forceinline__ float lrelu(float v, float s) { return v > 0.f ? v : v * s; }

__device__ __forceinline__ unsigned short f2bf(float f) {
    unsigned int u = __float_as_uint(f);
    u += 0x7FFFu + ((u >> 16) & 1u);
    return (unsigned short)(u >> 16);
}
__device__ __forceinline__ float bf2f(unsigned short u) {
    return __uint_as_float((unsigned int)u << 16);
}

__device__ __forceinline__ int ld_idx(const int* p, int e, int is64) {
    return is64 ? (int)(((const long long*)p)[e]) : p[e];
}

__global__ void detect_i64(const unsigned int* idx, int* flag) {
    if (blockIdx.x == 0 && threadIdx.x == 0) {
        int all0 = 1;
        for (int i = 1; i < 256; i += 2) {
            if (idx[i] != 0u) { all0 = 0; break; }
        }
        *flag = all0;
    }
}

// ---------------- conversions ----------------
__global__ void f32_to_bf16_vec(const float* __restrict__ in, unsigned short* __restrict__ out,
                                long long total)
{
    long long i = ((long long)blockIdx.x * blockDim.x + threadIdx.x) * 4;
    if (i + 4 <= total) {
        float4 v = *(const float4*)(in + i);
        ushort4 o;
        o.x = f2bf(v.x); o.y = f2bf(v.y); o.z = f2bf(v.z); o.w = f2bf(v.w);
        *(ushort4*)(out + i) = o;
    } else {
        for (; i < total; i++) out[i] = f2bf(in[i]);
    }
}

// builds w1t [512][256] = concat(W1l^T, W1r^T), w2t [128][256] = concat(W2l^T, W2r^T)
__global__ void prep_weights(const float* __restrict__ W1l, const float* __restrict__ W1r,
                             const float* __restrict__ W2l, const float* __restrict__ W2r,
                             unsigned short* __restrict__ w1t, unsigned short* __restrict__ w2t)
{
    int t = blockIdx.x * blockDim.x + threadIdx.x;
    if (t < 131072) {
        int nn = t >> 8, k = t & 255;
        float v = (nn < 256) ? W1l[k * 256 + nn] : W1r[k * 256 + (nn - 256)];
        w1t[t] = f2bf(v);
    } else if (t < 163840) {
        int u = t - 131072;
        int nn = u >> 8, k = u & 255;
        float v = (nn < 64) ? W2l[k * 64 + nn] : W2r[k * 64 + (nn - 64)];
        w2t[u] = f2bf(v);
    }
}

// ---------------- A-register-resident MFMA GEMM ----------------
// One block = 64 rows; wave w owns rows [bm + w*16, +16). A panel (16 x K) loaded
// once into registers (compile-time K -> fully unrolled); sweep N in NCHUNK-col
// chunks streaming B frags from L1/L2. C written as bf16 with split bias.
template <int N, int K, int NCHUNK>
__global__ __launch_bounds__(256) void gemm_areg(
    const unsigned short* __restrict__ A,   // [M,K] bf16
    const unsigned short* __restrict__ Bt,  // [N,K] bf16
    const float* __restrict__ biasL, const float* __restrict__ biasR, int NL,
    unsigned short* __restrict__ C, int M)
{
    constexpr int KF = K / 32;       // k-frags per row panel
    constexpr int NCF = NCHUNK / 16; // col-frags per chunk
    int w = threadIdx.x >> 6;
    int lane = threadIdx.x & 63;
    int r16 = lane & 15, kg = lane >> 4;
    int row = blockIdx.x * 64 + w * 16 + r16;
    int rowc = row < M ? row : 0;
    bf16x8 aF[KF];
#pragma unroll
    for (int k = 0; k < KF; k++)
        aF[k] = *(const bf16x8*)(A + (size_t)rowc * K + k * 32 + kg * 8);

    int rb = blockIdx.x * 64 + w * 16 + kg * 4;
    for (int c0 = 0; c0 < N; c0 += NCHUNK) {
        f32x4 acc[NCF] = {};
#pragma unroll
        for (int k = 0; k < KF; k++) {
#pragma unroll
            for (int nf = 0; nf < NCF; nf++) {
                bf16x8 b = *(const bf16x8*)(Bt + (size_t)(c0 + nf * 16 + r16) * K + k * 32 + kg * 8);
                acc[nf] = __builtin_amdgcn_mfma_f32_16x16x32_bf16(aF[k], b, acc[nf], 0, 0, 0);
            }
        }
#pragma unroll
        for (int nf = 0; nf < NCF; nf++) {
            int col = c0 + nf * 16 + r16;
            float bv = (col < NL) ? biasL[col] : biasR[col - NL];
#pragma unroll
            for (int r = 0; r < 4; r++) {
                int rr = rb + r;
                if (rr < M) C[(size_t)rr * N + col] = f2bf(acc[nf][r] + bv);
            }
        }
    }
}

// ---------------- CSR build ----------------
__global__ void hist_dst(const int* __restrict__ eidx, const int* __restrict__ flagp,
                         int E, int n, int* __restrict__ cnt)
{
    int t = blockIdx.x * blockDim.x + threadIdx.x;
    if (t >= E + n) return;
    int is64 = *flagp;
    int d = (t < E) ? ld_idx(eidx, E + t, is64) : (t - E);
    atomicAdd(&cnt[d], 1);
}

// multi-block exclusive scan
__global__ __launch_bounds__(1024) void scan1(const int* __restrict__ cnt,
                                              int* __restrict__ rowptr, int* __restrict__ psum, int n)
{
    __shared__ int wsum[16];
    int tid = threadIdx.x, lane = tid & 63, w = tid >> 6;
    int gid = blockIdx.x * 1024 + tid;
    int v = (gid < n) ? cnt[gid] : 0;
    int sc = v;
#pragma unroll
    for (int o = 1; o < 64; o <<= 1) { int t2 = __shfl_up(sc, o); if (lane >= o) sc += t2; }
    if (lane == 63) wsum[w] = sc;
    __syncthreads();
    if (tid < 16) {
        int t2 = wsum[tid];
#pragma unroll
        for (int o = 1; o < 16; o <<= 1) { int u = __shfl_up(t2, o); if (tid >= o) t2 += u; }
        wsum[tid] = t2;
    }
    __syncthreads();
    int wofs = w ? wsum[w - 1] : 0;
    if (gid < n) rowptr[gid] = wofs + sc - v;
    if (tid == 1023) psum[blockIdx.x] = wsum[15];
}

__global__ void scan2(const int* __restrict__ psum, int* __restrict__ pofs,
                      int* __restrict__ rowptr_n, int nb)
{
    int lane = threadIdx.x;
    int v = (lane < nb) ? psum[lane] : 0;
    int sc = v;
#pragma unroll
    for (int o = 1; o < 64; o <<= 1) { int t = __shfl_up(sc, o); if (lane >= o) sc += t; }
    if (lane < nb) pofs[lane] = sc - v;
    if (lane == 63) *rowptr_n = sc;
}

__global__ __launch_bounds__(1024) void scan3(int* __restrict__ rowptr,
                                              const int* __restrict__ pofs, int n)
{
    int gid = blockIdx.x * 1024 + threadIdx.x;
    if (gid < n) rowptr[gid] += pofs[blockIdx.x];
}

__global__ void scatter_edges(const int* __restrict__ eidx, const int* __restrict__ flagp,
                              int E, int n, const int* __restrict__ rowptr,
                              int* __restrict__ cursor, int* __restrict__ sord)
{
    int t = blockIdx.x * blockDim.x + threadIdx.x;
    if (t >= E + n) return;
    int is64 = *flagp;
    int s, d;
    if (t < E) { s = ld_idx(eidx, t, is64); d = ld_idx(eidx, E + t, is64); }
    else { s = t - E; d = s; }
    int pos = atomicAdd(&cursor[d], 1);
    sord[rowptr[d] + pos] = s;
}

// ---------------- fused edge phase, H=4: one wave per node, bf16 xlr[n][512] ----------------
#define SCORE4(p, xv) { float t_;                                   \
    t_ = xv.x + xrv.x; p  = fmaxf(t_, 0.2f * t_) * atv.x;           \
    t_ = xv.y + xrv.y; p += fmaxf(t_, 0.2f * t_) * atv.y;           \
    t_ = xv.z + xrv.z; p += fmaxf(t_, 0.2f * t_) * atv.z;           \
    t_ = xv.w + xrv.w; p += fmaxf(t_, 0.2f * t_) * atv.w; }

#define RED16(p) { p += __shfl_xor(p, 1); p += __shfl_xor(p, 2);    \
                   p += __shfl_xor(p, 4); p += __shfl_xor(p, 8); }

#define ONL(v, xv) { float nm = fmaxf(m, v); float sc = EXP2(m - nm); float ev = EXP2(v - nm); \
    ssum = ssum * sc + ev;                                           \
    o.x = o.x * sc + ev * xv.x; o.y = o.y * sc + ev * xv.y;          \
    o.z = o.z * sc + ev * xv.z; o.w = o.w * sc + ev * xv.w; m = nm; }

#define CVT4(f, u) float4 f = { bf2f(u.x), bf2f(u.y), bf2f(u.z), bf2f(u.w) };

__global__ __launch_bounds__(256) void node_attn_h4(
    const unsigned short* __restrict__ xlr,  // [n][512]: cols 0-255 = xl, 256-511 = xr
    const float* __restrict__ att, const float* __restrict__ bias,
    const int* __restrict__ rowptr, const int* __restrict__ sord, int n,
    unsigned short* __restrict__ outb)
{
    int d = (blockIdx.x * blockDim.x + threadIdx.x) >> 6;
    int lane = threadIdx.x & 63;
    if (d >= n) return;
    int off = (lane >> 4) * 64 + (lane & 15) * 4;  // h*64 + c0
    ushort4 xru = *(const ushort4*)(xlr + (size_t)d * 512 + 256 + off);
    CVT4(xrv, xru);
    float4 atv = *(const float4*)(att + off);
    int beg = rowptr[d], end = rowptr[d + 1];
    float m = -1e30f, ssum = 0.f;
    float4 o = {0.f, 0.f, 0.f, 0.f};
    for (int i = beg; i < end; i += 4) {
        int i1 = i + 1, i2 = i + 2, i3 = i + 3;
        int v1 = i1 < end, v2 = i2 < end, v3 = i3 < end;
        int s0 = sord[i];
        int s1 = sord[v1 ? i1 : i];
        int s2 = sord[v2 ? i2 : i];
        int s3 = sord[v3 ? i3 : i];
        ushort4 u0 = *(const ushort4*)(xlr + (size_t)s0 * 512 + off);
        ushort4 u1 = *(const ushort4*)(xlr + (size_t)s1 * 512 + off);
        ushort4 u2 = *(const ushort4*)(xlr + (size_t)s2 * 512 + off);
        ushort4 u3 = *(const ushort4*)(xlr + (size_t)s3 * 512 + off);
        CVT4(x0, u0); CVT4(x1, u1); CVT4(x2, u2); CVT4(x3, u3);
        float p0, p1, p2, p3;
        SCORE4(p0, x0); SCORE4(p1, x1); SCORE4(p2, x2); SCORE4(p3, x3);
        RED16(p0); RED16(p1); RED16(p2); RED16(p3);
        p0 *= LOG2E;
        p1 = v1 ? p1 * LOG2E : -1e30f;
        p2 = v2 ? p2 * LOG2E : -1e30f;
        p3 = v3 ? p3 * LOG2E : -1e30f;
        ONL(p0, x0); ONL(p1, x1); ONL(p2, x2); ONL(p3, x3);
    }
    float inv = 1.f / (ssum + 1e-16f);
    float4 bv = *(const float4*)(bias + off);
    float r0 = o.x * inv + bv.x, r1 = o.y * inv + bv.y;
    float r2 = o.z * inv + bv.z, r3 = o.w * inv + bv.w;
    r0 = fmaxf(r0, 0.01f * r0); r1 = fmaxf(r1, 0.01f * r1);
    r2 = fmaxf(r2, 0.01f * r2); r3 = fmaxf(r3, 0.01f * r3);
    ushort4 ov;
    ov.x = f2bf(r0); ov.y = f2bf(r1); ov.z = f2bf(r2); ov.w = f2bf(r3);
    *(ushort4*)(outb + (size_t)d * 256 + off) = ov;
}

// ---------------- fused edge phase, H=1: bf16 xlr2[n][128], 4+4 edges in flight ----------------
__global__ __launch_bounds__(256) void node_attn_h1(
    const unsigned short* __restrict__ xlr,  // [n][128]: 0-63 = xl, 64-127 = xr
    const float* __restrict__ att, const float* __restrict__ bias,
    const int* __restrict__ rowptr, const int* __restrict__ sord, int n,
    float* __restrict__ outf)
{
    int d = (blockIdx.x * blockDim.x + threadIdx.x) >> 6;
    int lane = threadIdx.x & 63;
    if (d >= n) return;
    int sg = lane >> 4, c0 = (lane & 15) * 4;
    ushort4 xru = *(const ushort4*)(xlr + (size_t)d * 128 + 64 + c0);
    CVT4(xrv, xru);
    float4 atv = *(const float4*)(att + c0);
    int beg = rowptr[d], end = rowptr[d + 1];
    float m = -1e30f, ssum = 0.f;
    float4 o = {0.f, 0.f, 0.f, 0.f};
    for (int i0 = beg; i0 < end; i0 += 8) {
        int ia = i0 + sg, ib = i0 + 4 + sg;
        int va = ia < end, vb = ib < end;
        int sa = sord[va ? ia : beg];
        int sb = sord[vb ? ib : beg];
        ushort4 ua = *(const ushort4*)(xlr + (size_t)sa * 128 + c0);
        ushort4 ub = *(const ushort4*)(xlr + (size_t)sb * 128 + c0);
        CVT4(xa, ua); CVT4(xb, ub);
        float pa, pb;
        SCORE4(pa, xa); SCORE4(pb, xb);
        RED16(pa); RED16(pb);
        pa = va ? pa * LOG2E : -1e30f;
        pb = vb ? pb * LOG2E : -1e30f;
        ONL(pa, xa); ONL(pb, xb);
    }
#pragma unroll
    for (int offs = 16; offs <= 32; offs <<= 1) {
        float m2 = __shfl_xor(m, offs);
        float s2 = __shfl_xor(ssum, offs);
        float4 o2;
        o2.x = __shfl_xor(o.x, offs); o2.y = __shfl_xor(o.y, offs);
        o2.z = __shfl_xor(o.z, offs); o2.w = __shfl_xor(o.w, offs);
        float nm = fmaxf(m, m2);
        float sa_ = EXP2(m - nm), sb_ = EXP2(m2 - nm);
        ssum = ssum * sa_ + s2 * sb_;
        o.x = o.x * sa_ + o2.x * sb_; o.y = o.y * sa_ + o2.y * sb_;
        o.z = o.z * sa_ + o2.z * sb_; o.w = o.w * sa_ + o2.w * sb_;
        m = nm;
    }
    if (sg == 0) {
        float inv = 1.f / (ssum + 1e-16f);
        float4 bv = *(const float4*)(bias + c0);
        float4 res;
        res.x = o.x * inv + bv.x; res.y = o.y * inv + bv.y;
        res.z = o.z * inv + bv.z; res.w = o.w * inv + bv.w;
        *(float4*)(outf + (size_t)d * 64 + c0) = res;
    }
}

// fused predict head
__global__ void predict_head(const float* __restrict__ h2,
                             const float* __restrict__ Wp1, const float* __restrict__ bp1,
                             const float* __restrict__ Wp2, const float* __restrict__ bp2,
                             float* __restrict__ logits, int n)
{
    int i = blockIdx.x * blockDim.x + threadIdx.x;
    if (i >= n) return;
    float h[64];
#pragma unroll
    for (int c = 0; c < 64; c++) h[c] = h2[(long long)i * 64 + c];
    float logit = bp2[0];
#pragma unroll
    for (int j = 0; j < 32; j++) {
        float z = bp1[j];
#pragma unroll
        for (int c = 0; c < 64; c++) z += h[c] * Wp1[c * 32 + j];
        z = lrelu(z, 0.01f);
        logit += z * Wp2[j];
    }
    logits[i] = logit;
}

extern "C" void kernel_launch(void* const* d_in, const int* in_sizes, int n_in,
                              void* d_out, int out_size, void* d_ws, size_t ws_size,
                              hipStream_t stream)
{
    const float* x    = (const float*)d_in[0];
    const int*   eidx = (const int*)d_in[1];
    const float* W1l  = (const float*)d_in[2];
    const float* b1l  = (const float*)d_in[3];
    const float* W1r  = (const float*)d_in[4];
    const float* b1r  = (const float*)d_in[5];
    const float* att1 = (const float*)d_in[6];
    const float* bias1= (const float*)d_in[7];
    const float* W2l  = (const float*)d_in[8];
    const float* b2l  = (const float*)d_in[9];
    const float* W2r  = (const float*)d_in[10];
    const float* b2r  = (const float*)d_in[11];
    const float* att2 = (const float*)d_in[12];
    const float* bias2= (const float*)d_in[13];
    const float* Wp1  = (const float*)d_in[14];
    const float* bp1  = (const float*)d_in[15];
    const float* Wp2  = (const float*)d_in[16];
    const float* bp2  = (const float*)d_in[17];

    const int n = in_sizes[0] / 256;  // 50000
    const int E = in_sizes[1] / 2;    // 600000
    const int Etot = E + n;
    const int nb = (n + 1023) / 1024;

    float* out = (float*)d_out;       // [0,n): logits ; [n, n+n*64): h
    unsigned short* ws16 = (unsigned short*)d_ws;

    // workspace layout (shorts)
    unsigned short* xb    = ws16;                       // n*256 bf16 (aliased: h1b)
    unsigned short* xlr1  = xb + (size_t)n * 256;       // n*512 bf16 (aliased: xlr2)
    unsigned short* w1t   = xlr1 + (size_t)n * 512;     // 512*256
    unsigned short* w2t   = w1t + 131072;               // 128*256
    int*            rowptr= (int*)(w2t + 32768);        // n+1
    int*            cnt   = rowptr + (n + 1);           // n
    int*            sord  = cnt + n;                    // Etot
    int*            psum  = sord + Etot;                // 64
    int*            pofs  = psum + 64;                  // 64
    int*            flagp = pofs + 64;                  // 1
    unsigned short* h1b   = xb;                         // attn1 out, gemm2 in
    unsigned short* xlr2  = xlr1;                       // n*128 bf16
    float*          h2    = out + n;

    detect_i64<<<1, 64, 0, stream>>>((const unsigned int*)eidx, flagp);

    // ---- CSR build ----
    hipMemsetAsync(cnt, 0, (size_t)n * sizeof(int), stream);
    hist_dst<<<(Etot + 255) / 256, 256, 0, stream>>>(eidx, flagp, E, n, cnt);
    scan1<<<nb, 1024, 0, stream>>>(cnt, rowptr, psum, n);
    scan2<<<1, 64, 0, stream>>>(psum, pofs, rowptr + n, nb);
    scan3<<<nb, 1024, 0, stream>>>(rowptr, pofs, n);
    hipMemsetAsync(cnt, 0, (size_t)n * sizeof(int), stream);
    scatter_edges<<<(Etot + 255) / 256, 256, 0, stream>>>(eidx, flagp, E, n, rowptr, cnt, sord);

    // ---- conversions ----
    {
        long long tot = (long long)n * 256;
        f32_to_bf16_vec<<<(int)((tot / 4 + 255) / 256), 256, 0, stream>>>(x, xb, tot);
        prep_weights<<<(163840 + 255) / 256, 256, 0, stream>>>(W1l, W1r, W2l, W2r, w1t, w2t);
    }

    const int gblocks = (n + 63) / 64;

    // ---- layer 1 projection (fused l|r, bf16 out, A-register-resident) ----
    gemm_areg<512, 256, 256><<<gblocks, 256, 0, stream>>>(xb, w1t, b1l, b1r, 256, xlr1, n);

    // ---- layer 1 edge phase ----
    node_attn_h4<<<(n + 3) / 4, 256, 0, stream>>>(xlr1, att1, bias1, rowptr, sord, n, h1b);

    // ---- layer 2 projection ----
    gemm_areg<128, 256, 128><<<gblocks, 256, 0, stream>>>(h1b, w2t, b2l, b2r, 64, xlr2, n);

    // ---- layer 2 edge phase ----
    node_attn_h1<<<(n + 3) / 4, 256, 0, stream>>>(xlr2, att2, bias2, rowptr, sord, n, h2);

    // ---- predict head ----
    predict_head<<<(n + 255) / 256, 256, 0, stream>>>(h2, Wp1, bp1, Wp2, bp2, out, n);
}

// Round 9
// 287.047 us; speedup vs baseline: 1.4251x; 1.4251x over previous
//
#include <hip/hip_runtime.h>

typedef __attribute__((ext_vector_type(8))) __bf16 bf16x8;
typedef __attribute__((ext_vector_type(4))) float f32x4;

#define EXP2 __builtin_amdgcn_exp2f
#define LOG2E 1.44269504f
#define MFMA __builtin_amdgcn_mfma_f32_16x16x32_bf16

__device__ __forceinline__ float lrelu(float v, float s) { return v > 0.f ? v : v * s; }

__device__ __forceinline__ unsigned short f2bf(float f) {
    unsigned int u = __float_as_uint(f);
    u += 0x7FFFu + ((u >> 16) & 1u);
    return (unsigned short)(u >> 16);
}
__device__ __forceinline__ float bf2f(unsigned short u) {
    return __uint_as_float((unsigned int)u << 16);
}

__device__ __forceinline__ int ld_idx(const int* p, int e, int is64) {
    return is64 ? (int)(((const long long*)p)[e]) : p[e];
}

__global__ void detect_i64(const unsigned int* idx, int* flag) {
    if (blockIdx.x == 0 && threadIdx.x == 0) {
        int all0 = 1;
        for (int i = 1; i < 256; i += 2) {
            if (idx[i] != 0u) { all0 = 0; break; }
        }
        *flag = all0;
    }
}

// ---------------- conversions (fragment-linear layouts) ----------------
// frag layout: chunk t = ((blk16*KF + kf)*64 + kg*16 + r16), holds 8 bf16 =
// elems [blk16*16 + r16][kf*32 + kg*8 .. +8]  (KF = K/32 = 8 for K=256)

// x [n][256] f32 -> xb frag (rows padded to nrb*16 with zeros)
__global__ void f32_to_bf16_frag(const float* __restrict__ in, unsigned short* __restrict__ out,
                                 int n, int nrb)
{
    int t = blockIdx.x * blockDim.x + threadIdx.x;
    if (t >= nrb * 512) return;                 // nrb * 8 * 64
    int lane = t & 63;
    int kf = (t >> 6) & 7;
    int rowblk = t >> 9;
    int r16 = lane & 15, kg = lane >> 4;
    int row = rowblk * 16 + r16;
    int k0 = kf * 32 + kg * 8;
    ushort4 o0 = {0, 0, 0, 0}, o1 = {0, 0, 0, 0};
    if (row < n) {
        float4 v0 = *(const float4*)(in + (size_t)row * 256 + k0);
        float4 v1 = *(const float4*)(in + (size_t)row * 256 + k0 + 4);
        o0.x = f2bf(v0.x); o0.y = f2bf(v0.y); o0.z = f2bf(v0.z); o0.w = f2bf(v0.w);
        o1.x = f2bf(v1.x); o1.y = f2bf(v1.y); o1.z = f2bf(v1.z); o1.w = f2bf(v1.w);
    }
    *(ushort4*)(out + (size_t)t * 8) = o0;
    *(ushort4*)(out + (size_t)t * 8 + 4) = o1;
}

// W1l|W1r -> w1t frag (col space 512), W2l|W2r -> w2t frag (col space 128)
__global__ void prep_weights_frag(const float* __restrict__ W1l, const float* __restrict__ W1r,
                                  const float* __restrict__ W2l, const float* __restrict__ W2r,
                                  unsigned short* __restrict__ w1t, unsigned short* __restrict__ w2t)
{
    int t = blockIdx.x * blockDim.x + threadIdx.x;
    const float *Wl, *Wr;
    unsigned short* dst;
    int NL, base;
    if (t < 16384)      { Wl = W1l; Wr = W1r; dst = w1t; NL = 256; base = t; }
    else if (t < 20480) { Wl = W2l; Wr = W2r; dst = w2t; NL = 64;  base = t - 16384; }
    else return;
    int lane = base & 63, kf = (base >> 6) & 7, colblk = base >> 9;
    int r16 = lane & 15, kg = lane >> 4;
    int col = colblk * 16 + r16;
    int k0 = kf * 32 + kg * 8;
    const float* W = (col < NL) ? Wl : Wr;
    int c = (col < NL) ? col : col - NL;
    unsigned short v[8];
#pragma unroll
    for (int e = 0; e < 8; e++) v[e] = f2bf(W[(size_t)(k0 + e) * NL + c]);
    ushort4 o0 = {v[0], v[1], v[2], v[3]}, o1 = {v[4], v[5], v[6], v[7]};
    *(ushort4*)(dst + (size_t)base * 8) = o0;
    *(ushort4*)(dst + (size_t)base * 8 + 4) = o1;
}

// ---------------- frag-layout MFMA GEMM ----------------
// A, Bt in frag layout. Wave = 2 rowblks x WCB colblks. All loads contiguous 1KB.
// C row-major bf16 with split bias. grid = (ceil(nrb/4), N/(32*WCB))
template <int N, int K, int WCB>
__global__ __launch_bounds__(256) void gemm_frag(
    const unsigned short* __restrict__ A, const unsigned short* __restrict__ Bt,
    const float* __restrict__ biasL, const float* __restrict__ biasR, int NL,
    unsigned short* __restrict__ C, int M, int nrb)
{
    constexpr int KF = K / 32;
    int wid = threadIdx.x >> 6, lane = threadIdx.x & 63;
    int wm = wid >> 1, wn = wid & 1;
    int rb0u = blockIdx.x * 4 + wm * 2;
    int cb0 = blockIdx.y * (2 * WCB) + wn * WCB;
    int rb0 = min(rb0u, nrb - 1), rb1 = min(rb0u + 1, nrb - 1);
    const unsigned short* A0 = A + ((size_t)rb0 * KF * 64 + lane) * 8;
    const unsigned short* A1 = A + ((size_t)rb1 * KF * 64 + lane) * 8;
    const unsigned short* B0 = Bt + ((size_t)cb0 * KF * 64 + lane) * 8;
    f32x4 acc[2][WCB] = {};
#pragma unroll
    for (int kf = 0; kf < KF; kf++) {
        bf16x8 a0 = *(const bf16x8*)(A0 + kf * 512);
        bf16x8 a1 = *(const bf16x8*)(A1 + kf * 512);
#pragma unroll
        for (int j = 0; j < WCB; j++) {
            bf16x8 b = *(const bf16x8*)(B0 + (size_t)j * KF * 512 + kf * 512);
            acc[0][j] = MFMA(a0, b, acc[0][j], 0, 0, 0);
            acc[1][j] = MFMA(a1, b, acc[1][j], 0, 0, 0);
        }
    }
    int ccol = lane & 15, crow = (lane >> 4) * 4;
#pragma unroll
    for (int i = 0; i < 2; i++) {
#pragma unroll
        for (int j = 0; j < WCB; j++) {
            int col = (cb0 + j) * 16 + ccol;
            float bv = (col < NL) ? biasL[col] : biasR[col - NL];
#pragma unroll
            for (int r = 0; r < 4; r++) {
                int row = (rb0u + i) * 16 + crow + r;
                if (row < M) C[(size_t)row * N + col] = f2bf(acc[i][j][r] + bv);
            }
        }
    }
}

// ---------------- CSR build ----------------
__global__ void hist_dst(const int* __restrict__ eidx, const int* __restrict__ flagp,
                         int E, int n, int* __restrict__ cnt)
{
    int t = blockIdx.x * blockDim.x + threadIdx.x;
    if (t >= E + n) return;
    int is64 = *flagp;
    int d = (t < E) ? ld_idx(eidx, E + t, is64) : (t - E);
    atomicAdd(&cnt[d], 1);
}

__global__ __launch_bounds__(1024) void scan1(const int* __restrict__ cnt,
                                              int* __restrict__ rowptr, int* __restrict__ psum, int n)
{
    __shared__ int wsum[16];
    int tid = threadIdx.x, lane = tid & 63, w = tid >> 6;
    int gid = blockIdx.x * 1024 + tid;
    int v = (gid < n) ? cnt[gid] : 0;
    int sc = v;
#pragma unroll
    for (int o = 1; o < 64; o <<= 1) { int t2 = __shfl_up(sc, o); if (lane >= o) sc += t2; }
    if (lane == 63) wsum[w] = sc;
    __syncthreads();
    if (tid < 16) {
        int t2 = wsum[tid];
#pragma unroll
        for (int o = 1; o < 16; o <<= 1) { int u = __shfl_up(t2, o); if (tid >= o) t2 += u; }
        wsum[tid] = t2;
    }
    __syncthreads();
    int wofs = w ? wsum[w - 1] : 0;
    if (gid < n) rowptr[gid] = wofs + sc - v;
    if (tid == 1023) psum[blockIdx.x] = wsum[15];
}

__global__ void scan2(const int* __restrict__ psum, int* __restrict__ pofs,
                      int* __restrict__ rowptr_n, int nb)
{
    int lane = threadIdx.x;
    int v = (lane < nb) ? psum[lane] : 0;
    int sc = v;
#pragma unroll
    for (int o = 1; o < 64; o <<= 1) { int t = __shfl_up(sc, o); if (lane >= o) sc += t; }
    if (lane < nb) pofs[lane] = sc - v;
    if (lane == 63) *rowptr_n = sc;
}

__global__ __launch_bounds__(1024) void scan3(int* __restrict__ rowptr,
                                              const int* __restrict__ pofs, int n)
{
    int gid = blockIdx.x * 1024 + threadIdx.x;
    if (gid < n) rowptr[gid] += pofs[blockIdx.x];
}

__global__ void scatter_edges(const int* __restrict__ eidx, const int* __restrict__ flagp,
                              int E, int n, const int* __restrict__ rowptr,
                              int* __restrict__ cursor, int* __restrict__ sord)
{
    int t = blockIdx.x * blockDim.x + threadIdx.x;
    if (t >= E + n) return;
    int is64 = *flagp;
    int s, d;
    if (t < E) { s = ld_idx(eidx, t, is64); d = ld_idx(eidx, E + t, is64); }
    else { s = t - E; d = s; }
    int pos = atomicAdd(&cursor[d], 1);
    sord[rowptr[d] + pos] = s;
}

// ---------------- fused edge phase, H=4 ----------------
#define SCORE4(p, xv) { float t_;                                   \
    t_ = xv.x + xrv.x; p  = fmaxf(t_, 0.2f * t_) * atv.x;           \
    t_ = xv.y + xrv.y; p += fmaxf(t_, 0.2f * t_) * atv.y;           \
    t_ = xv.z + xrv.z; p += fmaxf(t_, 0.2f * t_) * atv.z;           \
    t_ = xv.w + xrv.w; p += fmaxf(t_, 0.2f * t_) * atv.w; }

#define RED16(p) { p += __shfl_xor(p, 1); p += __shfl_xor(p, 2);    \
                   p += __shfl_xor(p, 4); p += __shfl_xor(p, 8); }

#define ONL(v, xv) { float nm = fmaxf(m, v); float sc = EXP2(m - nm); float ev = EXP2(v - nm); \
    ssum = ssum * sc + ev;                                           \
    o.x = o.x * sc + ev * xv.x; o.y = o.y * sc + ev * xv.y;          \
    o.z = o.z * sc + ev * xv.z; o.w = o.w * sc + ev * xv.w; m = nm; }

#define CVT4(f, u) float4 f = { bf2f(u.x), bf2f(u.y), bf2f(u.z), bf2f(u.w) };

__global__ __launch_bounds__(256) void node_attn_h4(
    const unsigned short* __restrict__ xlr,  // [n][512] row-major
    const float* __restrict__ att, const float* __restrict__ bias,
    const int* __restrict__ rowptr, const int* __restrict__ sord, int n,
    unsigned short* __restrict__ outb)       // frag layout (feeds gemm2)
{
    int d = (blockIdx.x * blockDim.x + threadIdx.x) >> 6;
    int lane = threadIdx.x & 63;
    if (d >= n) return;
    int off = (lane >> 4) * 64 + (lane & 15) * 4;  // h*64 + c0
    ushort4 xru = *(const ushort4*)(xlr + (size_t)d * 512 + 256 + off);
    CVT4(xrv, xru);
    float4 atv = *(const float4*)(att + off);
    int beg = rowptr[d], end = rowptr[d + 1];
    float m = -1e30f, ssum = 0.f;
    float4 o = {0.f, 0.f, 0.f, 0.f};
    for (int i = beg; i < end; i += 4) {
        int i1 = i + 1, i2 = i + 2, i3 = i + 3;
        int v1 = i1 < end, v2 = i2 < end, v3 = i3 < end;
        int s0 = sord[i];
        int s1 = sord[v1 ? i1 : i];
        int s2 = sord[v2 ? i2 : i];
        int s3 = sord[v3 ? i3 : i];
        ushort4 u0 = *(const ushort4*)(xlr + (size_t)s0 * 512 + off);
        ushort4 u1 = *(const ushort4*)(xlr + (size_t)s1 * 512 + off);
        ushort4 u2 = *(const ushort4*)(xlr + (size_t)s2 * 512 + off);
        ushort4 u3 = *(const ushort4*)(xlr + (size_t)s3 * 512 + off);
        CVT4(x0, u0); CVT4(x1, u1); CVT4(x2, u2); CVT4(x3, u3);
        float p0, p1, p2, p3;
        SCORE4(p0, x0); SCORE4(p1, x1); SCORE4(p2, x2); SCORE4(p3, x3);
        RED16(p0); RED16(p1); RED16(p2); RED16(p3);
        p0 *= LOG2E;
        p1 = v1 ? p1 * LOG2E : -1e30f;
        p2 = v2 ? p2 * LOG2E : -1e30f;
        p3 = v3 ? p3 * LOG2E : -1e30f;
        ONL(p0, x0); ONL(p1, x1); ONL(p2, x2); ONL(p3, x3);
    }
    float inv = 1.f / (ssum + 1e-16f);
    float4 bv = *(const float4*)(bias + off);
    float r0 = o.x * inv + bv.x, r1 = o.y * inv + bv.y;
    float r2 = o.z * inv + bv.z, r3 = o.w * inv + bv.w;
    r0 = fmaxf(r0, 0.01f * r0); r1 = fmaxf(r1, 0.01f * r1);
    r2 = fmaxf(r2, 0.01f * r2); r3 = fmaxf(r3, 0.01f * r3);
    ushort4 ov;
    ov.x = f2bf(r0); ov.y = f2bf(r1); ov.z = f2bf(r2); ov.w = f2bf(r3);
    // store in frag layout: row=d, cols off..off+3
    int rowblk = d >> 4, r16d = d & 15;
    int kf = off >> 5, kg2 = (off >> 3) & 3, e0 = off & 7;
    size_t flat = (((size_t)rowblk * 8 + kf) * 64 + kg2 * 16 + r16d) * 8 + e0;
    *(ushort4*)(outb + flat) = ov;
}

// ---------------- fused edge phase, H=1 ----------------
__global__ __launch_bounds__(256) void node_attn_h1(
    const unsigned short* __restrict__ xlr,  // [n][128] row-major
    const float* __restrict__ att, const float* __restrict__ bias,
    const int* __restrict__ rowptr, const int* __restrict__ sord, int n,
    float* __restrict__ outf)
{
    int d = (blockIdx.x * blockDim.x + threadIdx.x) >> 6;
    int lane = threadIdx.x & 63;
    if (d >= n) return;
    int sg = lane >> 4, c0 = (lane & 15) * 4;
    ushort4 xru = *(const ushort4*)(xlr + (size_t)d * 128 + 64 + c0);
    CVT4(xrv, xru);
    float4 atv = *(const float4*)(att + c0);
    int beg = rowptr[d], end = rowptr[d + 1];
    float m = -1e30f, ssum = 0.f;
    float4 o = {0.f, 0.f, 0.f, 0.f};
    for (int i0 = beg; i0 < end; i0 += 8) {
        int ia = i0 + sg, ib = i0 + 4 + sg;
        int va = ia < end, vb = ib < end;
        int sa = sord[va ? ia : beg];
        int sb = sord[vb ? ib : beg];
        ushort4 ua = *(const ushort4*)(xlr + (size_t)sa * 128 + c0);
        ushort4 ub = *(const ushort4*)(xlr + (size_t)sb * 128 + c0);
        CVT4(xa, ua); CVT4(xb, ub);
        float pa, pb;
        SCORE4(pa, xa); SCORE4(pb, xb);
        RED16(pa); RED16(pb);
        pa = va ? pa * LOG2E : -1e30f;
        pb = vb ? pb * LOG2E : -1e30f;
        ONL(pa, xa); ONL(pb, xb);
    }
#pragma unroll
    for (int offs = 16; offs <= 32; offs <<= 1) {
        float m2 = __shfl_xor(m, offs);
        float s2 = __shfl_xor(ssum, offs);
        float4 o2;
        o2.x = __shfl_xor(o.x, offs); o2.y = __shfl_xor(o.y, offs);
        o2.z = __shfl_xor(o.z, offs); o2.w = __shfl_xor(o.w, offs);
        float nm = fmaxf(m, m2);
        float sa_ = EXP2(m - nm), sb_ = EXP2(m2 - nm);
        ssum = ssum * sa_ + s2 * sb_;
        o.x = o.x * sa_ + o2.x * sb_; o.y = o.y * sa_ + o2.y * sb_;
        o.z = o.z * sa_ + o2.z * sb_; o.w = o.w * sa_ + o2.w * sb_;
        m = nm;
    }
    if (sg == 0) {
        float inv = 1.f / (ssum + 1e-16f);
        float4 bv = *(const float4*)(bias + c0);
        float4 res;
        res.x = o.x * inv + bv.x; res.y = o.y * inv + bv.y;
        res.z = o.z * inv + bv.z; res.w = o.w * inv + bv.w;
        *(float4*)(outf + (size_t)d * 64 + c0) = res;
    }
}

// fused predict head
__global__ void predict_head(const float* __restrict__ h2,
                             const float* __restrict__ Wp1, const float* __restrict__ bp1,
                             const float* __restrict__ Wp2, const float* __restrict__ bp2,
                             float* __restrict__ logits, int n)
{
    int i = blockIdx.x * blockDim.x + threadIdx.x;
    if (i >= n) return;
    float h[64];
#pragma unroll
    for (int c = 0; c < 64; c++) h[c] = h2[(long long)i * 64 + c];
    float logit = bp2[0];
#pragma unroll
    for (int j = 0; j < 32; j++) {
        float z = bp1[j];
#pragma unroll
        for (int c = 0; c < 64; c++) z += h[c] * Wp1[c * 32 + j];
        z = lrelu(z, 0.01f);
        logit += z * Wp2[j];
    }
    logits[i] = logit;
}

extern "C" void kernel_launch(void* const* d_in, const int* in_sizes, int n_in,
                              void* d_out, int out_size, void* d_ws, size_t ws_size,
                              hipStream_t stream)
{
    const float* x    = (const float*)d_in[0];
    const int*   eidx = (const int*)d_in[1];
    const float* W1l  = (const float*)d_in[2];
    const float* b1l  = (const float*)d_in[3];
    const float* W1r  = (const float*)d_in[4];
    const float* b1r  = (const float*)d_in[5];
    const float* att1 = (const float*)d_in[6];
    const float* bias1= (const float*)d_in[7];
    const float* W2l  = (const float*)d_in[8];
    const float* b2l  = (const float*)d_in[9];
    const float* W2r  = (const float*)d_in[10];
    const float* b2r  = (const float*)d_in[11];
    const float* att2 = (const float*)d_in[12];
    const float* bias2= (const float*)d_in[13];
    const float* Wp1  = (const float*)d_in[14];
    const float* bp1  = (const float*)d_in[15];
    const float* Wp2  = (const float*)d_in[16];
    const float* bp2  = (const float*)d_in[17];

    const int n = in_sizes[0] / 256;  // 50000
    const int E = in_sizes[1] / 2;    // 600000
    const int Etot = E + n;
    const int nb = (n + 1023) / 1024;
    const int nrb = (n + 15) / 16;    // 16-row blocks

    float* out = (float*)d_out;       // [0,n): logits ; [n, n+n*64): h
    unsigned short* ws16 = (unsigned short*)d_ws;

    // workspace layout (shorts)
    unsigned short* xb    = ws16;                         // nrb*4096 (frag; aliased h1b)
    unsigned short* xlr1  = xb + (size_t)nrb * 4096;      // n*512 row-major (aliased xlr2)
    unsigned short* w1t   = xlr1 + (size_t)n * 512;       // 131072 (frag)
    unsigned short* w2t   = w1t + 131072;                 // 32768 (frag)
    int*            rowptr= (int*)(w2t + 32768);          // n+1
    int*            cnt   = rowptr + (n + 1);             // n
    int*            sord  = cnt + n;                      // Etot
    int*            psum  = sord + Etot;                  // 64
    int*            pofs  = psum + 64;                    // 64
    int*            flagp = pofs + 64;                    // 1
    unsigned short* h1b   = xb;                           // attn1 out (frag), gemm2 in
    unsigned short* xlr2  = xlr1;                         // n*128 row-major
    float*          h2    = out + n;

    detect_i64<<<1, 64, 0, stream>>>((const unsigned int*)eidx, flagp);

    // ---- CSR build ----
    hipMemsetAsync(cnt, 0, (size_t)n * sizeof(int), stream);
    hist_dst<<<(Etot + 255) / 256, 256, 0, stream>>>(eidx, flagp, E, n, cnt);
    scan1<<<nb, 1024, 0, stream>>>(cnt, rowptr, psum, n);
    scan2<<<1, 64, 0, stream>>>(psum, pofs, rowptr + n, nb);
    scan3<<<nb, 1024, 0, stream>>>(rowptr, pofs, n);
    hipMemsetAsync(cnt, 0, (size_t)n * sizeof(int), stream);
    scatter_edges<<<(Etot + 255) / 256, 256, 0, stream>>>(eidx, flagp, E, n, rowptr, cnt, sord);

    // ---- conversions (frag layouts) ----
    f32_to_bf16_frag<<<(nrb * 512 + 255) / 256, 256, 0, stream>>>(x, xb, n, nrb);
    prep_weights_frag<<<(20480 + 255) / 256, 256, 0, stream>>>(W1l, W1r, W2l, W2r, w1t, w2t);

    const int gx = (nrb + 3) / 4;

    // ---- layer 1 projection: [n,256] @ [512,256]^T, wave = 2rb x 8cb, grid.y=2 ----
    {
        dim3 grid(gx, 2);
        gemm_frag<512, 256, 8><<<grid, 256, 0, stream>>>(xb, w1t, b1l, b1r, 256, xlr1, n, nrb);
    }

    // ---- layer 1 edge phase ----
    node_attn_h4<<<(n + 3) / 4, 256, 0, stream>>>(xlr1, att1, bias1, rowptr, sord, n, h1b);

    // ---- layer 2 projection: [n,256] @ [128,256]^T, wave = 2rb x 4cb, grid.y=1 ----
    {
        dim3 grid(gx, 1);
        gemm_frag<128, 256, 4><<<grid, 256, 0, stream>>>(h1b, w2t, b2l, b2r, 64, xlr2, n, nrb);
    }

    // ---- layer 2 edge phase ----
    node_attn_h1<<<(n + 3) / 4, 256, 0, stream>>>(xlr2, att2, bias2, rowptr, sord, n, h2);

    // ---- predict head ----
    predict_head<<<(n + 255) / 256, 256, 0, stream>>>(h2, Wp1, bp1, Wp2, bp2, out, n);
}

// Round 11
// 251.736 us; speedup vs baseline: 1.6250x; 1.1403x over previous
//
#include <hip/hip_runtime.h>

typedef __attribute__((ext_vector_type(8))) __bf16 bf16x8;
typedef __attribute__((ext_vector_type(4))) float f32x4;

#define EXP2 __builtin_amdgcn_exp2f
#define LOG2E 1.44269504f
#define MFMA __builtin_amdgcn_mfma_f32_16x16x32_bf16

__device__ __forceinline__ float lrelu(float v, float s) { return v > 0.f ? v : v * s; }

__device__ __forceinline__ unsigned short f2bf(float f) {
    unsigned int u = __float_as_uint(f);
    u += 0x7FFFu + ((u >> 16) & 1u);
    return (unsigned short)(u >> 16);
}
__device__ __forceinline__ float bf2f(unsigned short u) {
    return __uint_as_float((unsigned int)u << 16);
}

__device__ __forceinline__ int ld_idx(const int* p, int e, int is64) {
    return is64 ? (int)(((const long long*)p)[e]) : p[e];
}

__global__ void detect_i64(const unsigned int* idx, int* flag) {
    if (blockIdx.x == 0 && threadIdx.x == 0) {
        int all0 = 1;
        for (int i = 1; i < 256; i += 2) {
            if (idx[i] != 0u) { all0 = 0; break; }
        }
        *flag = all0;
    }
}

// ---------------- fused conversions (fragment-linear layouts) ----------------
// frag chunk t = ((blk16*KF + kf)*64 + kg*16 + r16) holds 8 bf16 =
// elems [blk16*16 + r16][kf*32 + kg*8 .. +8]  (KF = 8 for K=256)
__global__ void convert_all(const float* __restrict__ x,
                            const float* __restrict__ W1l, const float* __restrict__ W1r,
                            const float* __restrict__ W2l, const float* __restrict__ W2r,
                            unsigned short* __restrict__ xb,
                            unsigned short* __restrict__ w1t, unsigned short* __restrict__ w2t,
                            int n, int nrb)
{
    int t = blockIdx.x * blockDim.x + threadIdx.x;
    int A = nrb * 512;
    if (t < A) {
        int lane = t & 63;
        int kf = (t >> 6) & 7;
        int rowblk = t >> 9;
        int r16 = lane & 15, kg = lane >> 4;
        int row = rowblk * 16 + r16;
        int k0 = kf * 32 + kg * 8;
        ushort4 o0 = {0, 0, 0, 0}, o1 = {0, 0, 0, 0};
        if (row < n) {
            float4 v0 = *(const float4*)(x + (size_t)row * 256 + k0);
            float4 v1 = *(const float4*)(x + (size_t)row * 256 + k0 + 4);
            o0.x = f2bf(v0.x); o0.y = f2bf(v0.y); o0.z = f2bf(v0.z); o0.w = f2bf(v0.w);
            o1.x = f2bf(v1.x); o1.y = f2bf(v1.y); o1.z = f2bf(v1.z); o1.w = f2bf(v1.w);
        }
        *(ushort4*)(xb + (size_t)t * 8) = o0;
        *(ushort4*)(xb + (size_t)t * 8 + 4) = o1;
        return;
    }
    int tw = t - A;
    const float *Wl, *Wr;
    unsigned short* dst;
    int NL, base;
    if (tw < 16384)      { Wl = W1l; Wr = W1r; dst = w1t; NL = 256; base = tw; }
    else if (tw < 20480) { Wl = W2l; Wr = W2r; dst = w2t; NL = 64;  base = tw - 16384; }
    else return;
    int lane = base & 63, kf = (base >> 6) & 7, colblk = base >> 9;
    int r16 = lane & 15, kg = lane >> 4;
    int col = colblk * 16 + r16;
    int k0 = kf * 32 + kg * 8;
    const float* W = (col < NL) ? Wl : Wr;
    int c = (col < NL) ? col : col - NL;
    unsigned short v[8];
#pragma unroll
    for (int e = 0; e < 8; e++) v[e] = f2bf(W[(size_t)(k0 + e) * NL + c]);
    ushort4 o0 = {v[0], v[1], v[2], v[3]}, o1 = {v[4], v[5], v[6], v[7]};
    *(ushort4*)(dst + (size_t)base * 8) = o0;
    *(ushort4*)(dst + (size_t)base * 8 + 4) = o1;
}

// ---------------- frag-layout MFMA GEMM ----------------
template <int N, int K, int WCB>
__global__ __launch_bounds__(256) void gemm_frag(
    const unsigned short* __restrict__ A, const unsigned short* __restrict__ Bt,
    const float* __restrict__ biasL, const float* __restrict__ biasR, int NL,
    unsigned short* __restrict__ C, int M, int nrb)
{
    constexpr int KF = K / 32;
    int wid = threadIdx.x >> 6, lane = threadIdx.x & 63;
    int wm = wid >> 1, wn = wid & 1;
    int rb0u = blockIdx.x * 4 + wm * 2;
    int cb0 = blockIdx.y * (2 * WCB) + wn * WCB;
    int rb0 = min(rb0u, nrb - 1), rb1 = min(rb0u + 1, nrb - 1);
    const unsigned short* A0 = A + ((size_t)rb0 * KF * 64 + lane) * 8;
    const unsigned short* A1 = A + ((size_t)rb1 * KF * 64 + lane) * 8;
    const unsigned short* B0 = Bt + ((size_t)cb0 * KF * 64 + lane) * 8;
    f32x4 acc[2][WCB] = {};
#pragma unroll
    for (int kf = 0; kf < KF; kf++) {
        bf16x8 a0 = *(const bf16x8*)(A0 + kf * 512);
        bf16x8 a1 = *(const bf16x8*)(A1 + kf * 512);
#pragma unroll
        for (int j = 0; j < WCB; j++) {
            bf16x8 b = *(const bf16x8*)(B0 + (size_t)j * KF * 512 + kf * 512);
            acc[0][j] = MFMA(a0, b, acc[0][j], 0, 0, 0);
            acc[1][j] = MFMA(a1, b, acc[1][j], 0, 0, 0);
        }
    }
    int ccol = lane & 15, crow = (lane >> 4) * 4;
#pragma unroll
    for (int i = 0; i < 2; i++) {
#pragma unroll
        for (int j = 0; j < WCB; j++) {
            int col = (cb0 + j) * 16 + ccol;
            float bv = (col < NL) ? biasL[col] : biasR[col - NL];
#pragma unroll
            for (int r = 0; r < 4; r++) {
                int row = (rb0u + i) * 16 + crow + r;
                if (row < M) C[(size_t)row * N + col] = f2bf(acc[i][j][r] + bv);
            }
        }
    }
}

// ---------------- CSR build (single atomic pass) ----------------
__global__ void hist_dst_pos(const int* __restrict__ eidx, const int* __restrict__ flagp,
                             int E, int n, int* __restrict__ cnt, int* __restrict__ pos)
{
    int t = blockIdx.x * blockDim.x + threadIdx.x;
    if (t >= E + n) return;
    int is64 = *flagp;
    int d = (t < E) ? ld_idx(eidx, E + t, is64) : (t - E);
    pos[t] = atomicAdd(&cnt[d], 1);
}

__global__ __launch_bounds__(1024) void scan1(const int* __restrict__ cnt,
                                              int* __restrict__ rowptr, int* __restrict__ psum, int n)
{
    __shared__ int wsum[16];
    int tid = threadIdx.x, lane = tid & 63, w = tid >> 6;
    int gid = blockIdx.x * 1024 + tid;
    int v = (gid < n) ? cnt[gid] : 0;
    int sc = v;
#pragma unroll
    for (int o = 1; o < 64; o <<= 1) { int t2 = __shfl_up(sc, o); if (lane >= o) sc += t2; }
    if (lane == 63) wsum[w] = sc;
    __syncthreads();
    if (tid < 16) {
        int t2 = wsum[tid];
#pragma unroll
        for (int o = 1; o < 16; o <<= 1) { int u = __shfl_up(t2, o); if (tid >= o) t2 += u; }
        wsum[tid] = t2;
    }
    __syncthreads();
    int wofs = w ? wsum[w - 1] : 0;
    if (gid < n) rowptr[gid] = wofs + sc - v;
    if (tid == 1023) psum[blockIdx.x] = wsum[15];
}

__global__ void scan2(const int* __restrict__ psum, int* __restrict__ pofs,
                      int* __restrict__ rowptr_n, int nb)
{
    int lane = threadIdx.x;
    int v = (lane < nb) ? psum[lane] : 0;
    int sc = v;
#pragma unroll
    for (int o = 1; o < 64; o <<= 1) { int t = __shfl_up(sc, o); if (lane >= o) sc += t; }
    if (lane < nb) pofs[lane] = sc - v;
    if (lane == 63) *rowptr_n = sc;
}

__global__ __launch_bounds__(1024) void scan3(int* __restrict__ rowptr,
                                              const int* __restrict__ pofs, int n)
{
    int gid = blockIdx.x * 1024 + threadIdx.x;
    if (gid < n) rowptr[gid] += pofs[blockIdx.x];
}

__global__ void scatter_pos(const int* __restrict__ eidx, const int* __restrict__ flagp,
                            int E, int n, const int* __restrict__ rowptr,
                            const int* __restrict__ pos, int* __restrict__ sord)
{
    int t = blockIdx.x * blockDim.x + threadIdx.x;
    if (t >= E + n) return;
    int is64 = *flagp;
    int s, d;
    if (t < E) { s = ld_idx(eidx, t, is64); d = ld_idx(eidx, E + t, is64); }
    else { s = t - E; d = s; }
    sord[rowptr[d] + pos[t]] = s;
}

// ---------------- fused edge phase (no-max softmax: shift-invariant, scores |p|<~20) ----------------
// score via lrelu(t)*att = t*(0.6*att) + |t|*(0.4*att), LOG2E folded into att
#define SCOREX(p, xv) { float t_; p = 0.f;                              \
    t_ = xv.x + xrv.x; p = fmaf(t_, a6.x, p); p = fmaf(fabsf(t_), a4.x, p); \
    t_ = xv.y + xrv.y; p = fmaf(t_, a6.y, p); p = fmaf(fabsf(t_), a4.y, p); \
    t_ = xv.z + xrv.z; p = fmaf(t_, a6.z, p); p = fmaf(fabsf(t_), a4.z, p); \
    t_ = xv.w + xrv.w; p = fmaf(t_, a6.w, p); p = fmaf(fabsf(t_), a4.w, p); }

#define RED16(p) { p += __shfl_xor(p, 1); p += __shfl_xor(p, 2);    \
                   p += __shfl_xor(p, 4); p += __shfl_xor(p, 8); }

#define EACC(v, xv) { float ev = EXP2(v); ssum += ev;                \
    o.x = fmaf(ev, xv.x, o.x); o.y = fmaf(ev, xv.y, o.y);            \
    o.z = fmaf(ev, xv.z, o.z); o.w = fmaf(ev, xv.w, o.w); }

#define CVT4(f, u) float4 f = { bf2f(u.x), bf2f(u.y), bf2f(u.z), bf2f(u.w) };

__global__ __launch_bounds__(256) void node_attn_h4(
    const unsigned short* __restrict__ xlr,  // [n][512] row-major
    const float* __restrict__ att, const float* __restrict__ bias,
    const int* __restrict__ rowptr, const int* __restrict__ sord, int n,
    unsigned short* __restrict__ outb)       // frag layout (feeds gemm2)
{
    int d = (blockIdx.x * blockDim.x + threadIdx.x) >> 6;
    int lane = threadIdx.x & 63;
    if (d >= n) return;
    int off = (lane >> 4) * 64 + (lane & 15) * 4;  // h*64 + c0
    ushort4 xru = *(const ushort4*)(xlr + (size_t)d * 512 + 256 + off);
    CVT4(xrv, xru);
    float4 atv = *(const float4*)(att + off);
    float4 a6, a4;
    a6.x = atv.x * (0.6f * LOG2E); a6.y = atv.y * (0.6f * LOG2E);
    a6.z = atv.z * (0.6f * LOG2E); a6.w = atv.w * (0.6f * LOG2E);
    a4.x = atv.x * (0.4f * LOG2E); a4.y = atv.y * (0.4f * LOG2E);
    a4.z = atv.z * (0.4f * LOG2E); a4.w = atv.w * (0.4f * LOG2E);
    int beg = rowptr[d], end = rowptr[d + 1];
    float ssum = 0.f;
    float4 o = {0.f, 0.f, 0.f, 0.f};
    for (int i = beg; i < end; i += 4) {
        int i1 = i + 1, i2 = i + 2, i3 = i + 3;
        int v1 = i1 < end, v2 = i2 < end, v3 = i3 < end;
        int s0 = sord[i];
        int s1 = sord[v1 ? i1 : i];
        int s2 = sord[v2 ? i2 : i];
        int s3 = sord[v3 ? i3 : i];
        ushort4 u0 = *(const ushort4*)(xlr + (size_t)s0 * 512 + off);
        ushort4 u1 = *(const ushort4*)(xlr + (size_t)s1 * 512 + off);
        ushort4 u2 = *(const ushort4*)(xlr + (size_t)s2 * 512 + off);
        ushort4 u3 = *(const ushort4*)(xlr + (size_t)s3 * 512 + off);
        CVT4(x0, u0); CVT4(x1, u1); CVT4(x2, u2); CVT4(x3, u3);
        float p0, p1, p2, p3;
        SCOREX(p0, x0); SCOREX(p1, x1); SCOREX(p2, x2); SCOREX(p3, x3);
        RED16(p0); RED16(p1); RED16(p2); RED16(p3);
        p1 = v1 ? p1 : -1e30f;
        p2 = v2 ? p2 : -1e30f;
        p3 = v3 ? p3 : -1e30f;
        EACC(p0, x0); EACC(p1, x1); EACC(p2, x2); EACC(p3, x3);
    }
    float inv = 1.f / (ssum + 1e-16f);
    float4 bv = *(const float4*)(bias + off);
    float r0 = o.x * inv + bv.x, r1 = o.y * inv + bv.y;
    float r2 = o.z * inv + bv.z, r3 = o.w * inv + bv.w;
    r0 = fmaxf(r0, 0.01f * r0); r1 = fmaxf(r1, 0.01f * r1);
    r2 = fmaxf(r2, 0.01f * r2); r3 = fmaxf(r3, 0.01f * r3);
    ushort4 ov;
    ov.x = f2bf(r0); ov.y = f2bf(r1); ov.z = f2bf(r2); ov.w = f2bf(r3);
    // store in frag layout: row=d, cols off..off+3
    int rowblk = d >> 4, r16d = d & 15;
    int kf = off >> 5, kg2 = (off >> 3) & 3, e0 = off & 7;
    size_t flat = (((size_t)rowblk * 8 + kf) * 64 + kg2 * 16 + r16d) * 8 + e0;
    *(ushort4*)(outb + flat) = ov;
}

// ---------------- fused edge phase, H=1 (no-max) ----------------
__global__ __launch_bounds__(256) void node_attn_h1(
    const unsigned short* __restrict__ xlr,  // [n][128] row-major
    const float* __restrict__ att, const float* __restrict__ bias,
    const int* __restrict__ rowptr, const int* __restrict__ sord, int n,
    float* __restrict__ outf)
{
    int d = (blockIdx.x * blockDim.x + threadIdx.x) >> 6;
    int lane = threadIdx.x & 63;
    if (d >= n) return;
    int sg = lane >> 4, c0 = (lane & 15) * 4;
    ushort4 xru = *(const ushort4*)(xlr + (size_t)d * 128 + 64 + c0);
    CVT4(xrv, xru);
    float4 atv = *(const float4*)(att + c0);
    float4 a6, a4;
    a6.x = atv.x * (0.6f * LOG2E); a6.y = atv.y * (0.6f * LOG2E);
    a6.z = atv.z * (0.6f * LOG2E); a6.w = atv.w * (0.6f * LOG2E);
    a4.x = atv.x * (0.4f * LOG2E); a4.y = atv.y * (0.4f * LOG2E);
    a4.z = atv.z * (0.4f * LOG2E); a4.w = atv.w * (0.4f * LOG2E);
    int beg = rowptr[d], end = rowptr[d + 1];
    float ssum = 0.f;
    float4 o = {0.f, 0.f, 0.f, 0.f};
    for (int i0 = beg; i0 < end; i0 += 8) {
        int ia = i0 + sg, ib = i0 + 4 + sg;
        int va = ia < end, vb = ib < end;
        int sa = sord[va ? ia : beg];
        int sb = sord[vb ? ib : beg];
        ushort4 ua = *(const ushort4*)(xlr + (size_t)sa * 128 + c0);
        ushort4 ub = *(const ushort4*)(xlr + (size_t)sb * 128 + c0);
        CVT4(xa, ua); CVT4(xb, ub);
        float pa, pb;
        SCOREX(pa, xa); SCOREX(pb, xb);
        RED16(pa); RED16(pb);
        pa = va ? pa : -1e30f;
        pb = vb ? pb : -1e30f;
        EACC(pa, xa); EACC(pb, xb);
    }
    // plain-sum merge of the 4 subgroup states
#pragma unroll
    for (int offs = 16; offs <= 32; offs <<= 1) {
        ssum += __shfl_xor(ssum, offs);
        o.x += __shfl_xor(o.x, offs); o.y += __shfl_xor(o.y, offs);
        o.z += __shfl_xor(o.z, offs); o.w += __shfl_xor(o.w, offs);
    }
    if (sg == 0) {
        float inv = 1.f / (ssum + 1e-16f);
        float4 bv = *(const float4*)(bias + c0);
        float4 res;
        res.x = o.x * inv + bv.x; res.y = o.y * inv + bv.y;
        res.z = o.z * inv + bv.z; res.w = o.w * inv + bv.w;
        *(float4*)(outf + (size_t)d * 64 + c0) = res;
    }
}

// fused predict head
__global__ void predict_head(const float* __restrict__ h2,
                             const float* __restrict__ Wp1, const float* __restrict__ bp1,
                             const float* __restrict__ Wp2, const float* __restrict__ bp2,
                             float* __restrict__ logits, int n)
{
    int i = blockIdx.x * blockDim.x + threadIdx.x;
    if (i >= n) return;
    float h[64];
#pragma unroll
    for (int c = 0; c < 64; c++) h[c] = h2[(long long)i * 64 + c];
    float logit = bp2[0];
#pragma unroll
    for (int j = 0; j < 32; j++) {
        float z = bp1[j];
#pragma unroll
        for (int c = 0; c < 64; c++) z += h[c] * Wp1[c * 32 + j];
        z = lrelu(z, 0.01f);
        logit += z * Wp2[j];
    }
    logits[i] = logit;
}

extern "C" void kernel_launch(void* const* d_in, const int* in_sizes, int n_in,
                              void* d_out, int out_size, void* d_ws, size_t ws_size,
                              hipStream_t stream)
{
    const float* x    = (const float*)d_in[0];
    const int*   eidx = (const int*)d_in[1];
    const float* W1l  = (const float*)d_in[2];
    const float* b1l  = (const float*)d_in[3];
    const float* W1r  = (const float*)d_in[4];
    const float* b1r  = (const float*)d_in[5];
    const float* att1 = (const float*)d_in[6];
    const float* bias1= (const float*)d_in[7];
    const float* W2l  = (const float*)d_in[8];
    const float* b2l  = (const float*)d_in[9];
    const float* W2r  = (const float*)d_in[10];
    const float* b2r  = (const float*)d_in[11];
    const float* att2 = (const float*)d_in[12];
    const float* bias2= (const float*)d_in[13];
    const float* Wp1  = (const float*)d_in[14];
    const float* bp1  = (const float*)d_in[15];
    const float* Wp2  = (const float*)d_in[16];
    const float* bp2  = (const float*)d_in[17];

    const int n = in_sizes[0] / 256;  // 50000
    const int E = in_sizes[1] / 2;    // 600000
    const int Etot = E + n;
    const int nb = (n + 1023) / 1024;
    const int nrb = (n + 15) / 16;    // 16-row blocks

    float* out = (float*)d_out;       // [0,n): logits ; [n, n+n*64): h
    unsigned short* ws16 = (unsigned short*)d_ws;

    // workspace layout (shorts)
    unsigned short* xb    = ws16;                         // nrb*4096 (frag; aliased h1b)
    unsigned short* xlr1  = xb + (size_t)nrb * 4096;      // n*512 row-major (aliased xlr2)
    unsigned short* w1t   = xlr1 + (size_t)n * 512;       // 131072 (frag)
    unsigned short* w2t   = w1t + 131072;                 // 32768 (frag)
    int*            rowptr= (int*)(w2t + 32768);          // n+1
    int*            cnt   = rowptr + (n + 1);             // n
    int*            sord  = cnt + n;                      // Etot
    int*            pos   = sord + Etot;                  // Etot
    int*            psum  = pos + Etot;                   // 64
    int*            pofs  = psum + 64;                    // 64
    int*            flagp = pofs + 64;                    // 1
    unsigned short* h1b   = xb;                           // attn1 out (frag), gemm2 in
    unsigned short* xlr2  = xlr1;                         // n*128 row-major
    float*          h2    = out + n;

    detect_i64<<<1, 64, 0, stream>>>((const unsigned int*)eidx, flagp);

    // ---- CSR build (one atomic pass) ----
    hipMemsetAsync(cnt, 0, (size_t)n * sizeof(int), stream);
    hist_dst_pos<<<(Etot + 255) / 256, 256, 0, stream>>>(eidx, flagp, E, n, cnt, pos);
    scan1<<<nb, 1024, 0, stream>>>(cnt, rowptr, psum, n);
    scan2<<<1, 64, 0, stream>>>(psum, pofs, rowptr + n, nb);
    scan3<<<nb, 1024, 0, stream>>>(rowptr, pofs, n);
    scatter_pos<<<(Etot + 255) / 256, 256, 0, stream>>>(eidx, flagp, E, n, rowptr, pos, sord);

    // ---- conversions (frag layouts, single launch) ----
    convert_all<<<(nrb * 512 + 20480 + 255) / 256, 256, 0, stream>>>(
        x, W1l, W1r, W2l, W2r, xb, w1t, w2t, n, nrb);

    const int gx = (nrb + 3) / 4;

    // ---- layer 1 projection: [n,256] @ [512,256]^T ----
    {
        dim3 grid(gx, 2);
        gemm_frag<512, 256, 8><<<grid, 256, 0, stream>>>(xb, w1t, b1l, b1r, 256, xlr1, n, nrb);
    }

    // ---- layer 1 edge phase ----
    node_attn_h4<<<(n + 3) / 4, 256, 0, stream>>>(xlr1, att1, bias1, rowptr, sord, n, h1b);

    // ---- layer 2 projection: [n,256] @ [128,256]^T ----
    {
        dim3 grid(gx, 1);
        gemm_frag<128, 256, 4><<<grid, 256, 0, stream>>>(h1b, w2t, b2l, b2r, 64, xlr2, n, nrb);
    }

    // ---- layer 2 edge phase ----
    node_attn_h1<<<(n + 3) / 4, 256, 0, stream>>>(xlr2, att2, bias2, rowptr, sord, n, h2);

    // ---- predict head ----
    predict_head<<<(n + 255) / 256, 256, 0, stream>>>(h2, Wp1, bp1, Wp2, bp2, out, n);
}

// Round 12
// 249.201 us; speedup vs baseline: 1.6416x; 1.0102x over previous
//
#include <hip/hip_runtime.h>

typedef __attribute__((ext_vector_type(8))) __bf16 bf16x8;
typedef __attribute__((ext_vector_type(4))) float f32x4;

#define EXP2 __builtin_amdgcn_exp2f
#define LOG2E 1.44269504f
#define MFMA __builtin_amdgcn_mfma_f32_16x16x32_bf16

__device__ __forceinline__ float lrelu(float v, float s) { return v > 0.f ? v : v * s; }

__device__ __forceinline__ unsigned short f2bf(float f) {
    unsigned int u = __float_as_uint(f);
    u += 0x7FFFu + ((u >> 16) & 1u);
    return (unsigned short)(u >> 16);
}
__device__ __forceinline__ float bf2f(unsigned short u) {
    return __uint_as_float((unsigned int)u << 16);
}

__device__ __forceinline__ int ld_idx(const int* p, int e, int is64) {
    return is64 ? (int)(((const long long*)p)[e]) : p[e];
}

__global__ void detect_i64(const unsigned int* idx, int* flag) {
    if (blockIdx.x == 0 && threadIdx.x == 0) {
        int all0 = 1;
        for (int i = 1; i < 256; i += 2) {
            if (idx[i] != 0u) { all0 = 0; break; }
        }
        *flag = all0;
    }
}

// ---------------- fused conversions (fragment-linear layouts) ----------------
// frag chunk t = ((blk16*KF + kf)*64 + kg*16 + r16) holds 8 bf16 =
// elems [blk16*16 + r16][kf*32 + kg*8 .. +8]  (KF = 8 for K=256)
__global__ void convert_all(const float* __restrict__ x,
                            const float* __restrict__ W1l, const float* __restrict__ W1r,
                            const float* __restrict__ W2l, const float* __restrict__ W2r,
                            unsigned short* __restrict__ xb,
                            unsigned short* __restrict__ w1t, unsigned short* __restrict__ w2t,
                            int n, int nrb)
{
    int t = blockIdx.x * blockDim.x + threadIdx.x;
    int A = nrb * 512;
    if (t < A) {
        int lane = t & 63;
        int kf = (t >> 6) & 7;
        int rowblk = t >> 9;
        int r16 = lane & 15, kg = lane >> 4;
        int row = rowblk * 16 + r16;
        int k0 = kf * 32 + kg * 8;
        ushort4 o0 = {0, 0, 0, 0}, o1 = {0, 0, 0, 0};
        if (row < n) {
            float4 v0 = *(const float4*)(x + (size_t)row * 256 + k0);
            float4 v1 = *(const float4*)(x + (size_t)row * 256 + k0 + 4);
            o0.x = f2bf(v0.x); o0.y = f2bf(v0.y); o0.z = f2bf(v0.z); o0.w = f2bf(v0.w);
            o1.x = f2bf(v1.x); o1.y = f2bf(v1.y); o1.z = f2bf(v1.z); o1.w = f2bf(v1.w);
        }
        *(ushort4*)(xb + (size_t)t * 8) = o0;
        *(ushort4*)(xb + (size_t)t * 8 + 4) = o1;
        return;
    }
    int tw = t - A;
    const float *Wl, *Wr;
    unsigned short* dst;
    int NL, base;
    if (tw < 16384)      { Wl = W1l; Wr = W1r; dst = w1t; NL = 256; base = tw; }
    else if (tw < 20480) { Wl = W2l; Wr = W2r; dst = w2t; NL = 64;  base = tw - 16384; }
    else return;
    int lane = base & 63, kf = (base >> 6) & 7, colblk = base >> 9;
    int r16 = lane & 15, kg = lane >> 4;
    int col = colblk * 16 + r16;
    int k0 = kf * 32 + kg * 8;
    const float* W = (col < NL) ? Wl : Wr;
    int c = (col < NL) ? col : col - NL;
    unsigned short v[8];
#pragma unroll
    for (int e = 0; e < 8; e++) v[e] = f2bf(W[(size_t)(k0 + e) * NL + c]);
    ushort4 o0 = {v[0], v[1], v[2], v[3]}, o1 = {v[4], v[5], v[6], v[7]};
    *(ushort4*)(dst + (size_t)base * 8) = o0;
    *(ushort4*)(dst + (size_t)base * 8 + 4) = o1;
}

// ---------------- frag-layout MFMA GEMM ----------------
// RB rowblks per wave (B-frag reused across RB MFMAs -> latency hiding at
// reg-capped 2 waves/SIMD). Block = 2wm x 2wn waves.
template <int N, int K, int RB, int WCB>
__global__ __launch_bounds__(256) void gemm_frag(
    const unsigned short* __restrict__ A, const unsigned short* __restrict__ Bt,
    const float* __restrict__ biasL, const float* __restrict__ biasR, int NL,
    unsigned short* __restrict__ C, int M, int nrb)
{
    constexpr int KF = K / 32;
    int wid = threadIdx.x >> 6, lane = threadIdx.x & 63;
    int wm = wid >> 1, wn = wid & 1;
    int rbase = (blockIdx.x * 2 + wm) * RB;
    int cb0 = blockIdx.y * (2 * WCB) + wn * WCB;
    const unsigned short* Ap[RB];
#pragma unroll
    for (int r = 0; r < RB; r++) {
        int rb = min(rbase + r, nrb - 1);
        Ap[r] = A + ((size_t)rb * KF * 64 + lane) * 8;
    }
    const unsigned short* B0 = Bt + ((size_t)cb0 * KF * 64 + lane) * 8;
    f32x4 acc[RB][WCB] = {};
#pragma unroll
    for (int kf = 0; kf < KF; kf++) {
        bf16x8 a[RB];
#pragma unroll
        for (int r = 0; r < RB; r++) a[r] = *(const bf16x8*)(Ap[r] + kf * 512);
#pragma unroll
        for (int j = 0; j < WCB; j++) {
            bf16x8 b = *(const bf16x8*)(B0 + (size_t)j * KF * 512 + kf * 512);
#pragma unroll
            for (int r = 0; r < RB; r++) acc[r][j] = MFMA(a[r], b, acc[r][j], 0, 0, 0);
        }
    }
    int ccol = lane & 15, crow = (lane >> 4) * 4;
#pragma unroll
    for (int r = 0; r < RB; r++) {
#pragma unroll
        for (int j = 0; j < WCB; j++) {
            int col = (cb0 + j) * 16 + ccol;
            float bv = (col < NL) ? biasL[col] : biasR[col - NL];
#pragma unroll
            for (int q = 0; q < 4; q++) {
                int row = (rbase + r) * 16 + crow + q;
                if (row < M) C[(size_t)row * N + col] = f2bf(acc[r][j][q] + bv);
            }
        }
    }
}

// ---------------- CSR build (single atomic pass) ----------------
__global__ void hist_dst_pos(const int* __restrict__ eidx, const int* __restrict__ flagp,
                             int E, int n, int* __restrict__ cnt, int* __restrict__ pos)
{
    int t = blockIdx.x * blockDim.x + threadIdx.x;
    if (t >= E + n) return;
    int is64 = *flagp;
    int d = (t < E) ? ld_idx(eidx, E + t, is64) : (t - E);
    pos[t] = atomicAdd(&cnt[d], 1);
}

__global__ __launch_bounds__(1024) void scan1(const int* __restrict__ cnt,
                                              int* __restrict__ rowptr, int* __restrict__ psum, int n)
{
    __shared__ int wsum[16];
    int tid = threadIdx.x, lane = tid & 63, w = tid >> 6;
    int gid = blockIdx.x * 1024 + tid;
    int v = (gid < n) ? cnt[gid] : 0;
    int sc = v;
#pragma unroll
    for (int o = 1; o < 64; o <<= 1) { int t2 = __shfl_up(sc, o); if (lane >= o) sc += t2; }
    if (lane == 63) wsum[w] = sc;
    __syncthreads();
    if (tid < 16) {
        int t2 = wsum[tid];
#pragma unroll
        for (int o = 1; o < 16; o <<= 1) { int u = __shfl_up(t2, o); if (tid >= o) t2 += u; }
        wsum[tid] = t2;
    }
    __syncthreads();
    int wofs = w ? wsum[w - 1] : 0;
    if (gid < n) rowptr[gid] = wofs + sc - v;
    if (tid == 1023) psum[blockIdx.x] = wsum[15];
}

__global__ void scan2(const int* __restrict__ psum, int* __restrict__ pofs,
                      int* __restrict__ rowptr_n, int nb)
{
    int lane = threadIdx.x;
    int v = (lane < nb) ? psum[lane] : 0;
    int sc = v;
#pragma unroll
    for (int o = 1; o < 64; o <<= 1) { int t = __shfl_up(sc, o); if (lane >= o) sc += t; }
    if (lane < nb) pofs[lane] = sc - v;
    if (lane == 63) *rowptr_n = sc;
}

__global__ __launch_bounds__(1024) void scan3(int* __restrict__ rowptr,
                                              const int* __restrict__ pofs, int n)
{
    int gid = blockIdx.x * 1024 + threadIdx.x;
    if (gid < n) rowptr[gid] += pofs[blockIdx.x];
}

__global__ void scatter_pos(const int* __restrict__ eidx, const int* __restrict__ flagp,
                            int E, int n, const int* __restrict__ rowptr,
                            const int* __restrict__ pos, int* __restrict__ sord)
{
    int t = blockIdx.x * blockDim.x + threadIdx.x;
    if (t >= E + n) return;
    int is64 = *flagp;
    int s, d;
    if (t < E) { s = ld_idx(eidx, t, is64); d = ld_idx(eidx, E + t, is64); }
    else { s = t - E; d = s; }
    sord[rowptr[d] + pos[t]] = s;
}

// ---------------- fused edge phase (no-max softmax: shift-invariant, scores |p|<~20) ----------------
// score via lrelu(t)*att = t*(0.6*att) + |t|*(0.4*att), LOG2E folded into att
#define SCOREX(p, xv) { float t_; p = 0.f;                              \
    t_ = xv.x + xrv.x; p = fmaf(t_, a6.x, p); p = fmaf(fabsf(t_), a4.x, p); \
    t_ = xv.y + xrv.y; p = fmaf(t_, a6.y, p); p = fmaf(fabsf(t_), a4.y, p); \
    t_ = xv.z + xrv.z; p = fmaf(t_, a6.z, p); p = fmaf(fabsf(t_), a4.z, p); \
    t_ = xv.w + xrv.w; p = fmaf(t_, a6.w, p); p = fmaf(fabsf(t_), a4.w, p); }

#define RED16(p) { p += __shfl_xor(p, 1); p += __shfl_xor(p, 2);    \
                   p += __shfl_xor(p, 4); p += __shfl_xor(p, 8); }

#define EACC(v, xv) { float ev = EXP2(v); ssum += ev;                \
    o.x = fmaf(ev, xv.x, o.x); o.y = fmaf(ev, xv.y, o.y);            \
    o.z = fmaf(ev, xv.z, o.z); o.w = fmaf(ev, xv.w, o.w); }

#define CVT4(f, u) float4 f = { bf2f(u.x), bf2f(u.y), bf2f(u.z), bf2f(u.w) };

__global__ __launch_bounds__(256) void node_attn_h4(
    const unsigned short* __restrict__ xlr,  // [n][512] row-major
    const float* __restrict__ att, const float* __restrict__ bias,
    const int* __restrict__ rowptr, const int* __restrict__ sord, int n,
    unsigned short* __restrict__ outb)       // frag layout (feeds gemm2)
{
    int d = (blockIdx.x * blockDim.x + threadIdx.x) >> 6;
    int lane = threadIdx.x & 63;
    if (d >= n) return;
    int off = (lane >> 4) * 64 + (lane & 15) * 4;  // h*64 + c0
    ushort4 xru = *(const ushort4*)(xlr + (size_t)d * 512 + 256 + off);
    CVT4(xrv, xru);
    float4 atv = *(const float4*)(att + off);
    float4 a6, a4;
    a6.x = atv.x * (0.6f * LOG2E); a6.y = atv.y * (0.6f * LOG2E);
    a6.z = atv.z * (0.6f * LOG2E); a6.w = atv.w * (0.6f * LOG2E);
    a4.x = atv.x * (0.4f * LOG2E); a4.y = atv.y * (0.4f * LOG2E);
    a4.z = atv.z * (0.4f * LOG2E); a4.w = atv.w * (0.4f * LOG2E);
    int beg = rowptr[d], end = rowptr[d + 1];
    float ssum = 0.f;
    float4 o = {0.f, 0.f, 0.f, 0.f};
    for (int i = beg; i < end; i += 4) {
        int i1 = i + 1, i2 = i + 2, i3 = i + 3;
        int v1 = i1 < end, v2 = i2 < end, v3 = i3 < end;
        int s0 = sord[i];
        int s1 = sord[v1 ? i1 : i];
        int s2 = sord[v2 ? i2 : i];
        int s3 = sord[v3 ? i3 : i];
        ushort4 u0 = *(const ushort4*)(xlr + (size_t)s0 * 512 + off);
        ushort4 u1 = *(const ushort4*)(xlr + (size_t)s1 * 512 + off);
        ushort4 u2 = *(const ushort4*)(xlr + (size_t)s2 * 512 + off);
        ushort4 u3 = *(const ushort4*)(xlr + (size_t)s3 * 512 + off);
        CVT4(x0, u0); CVT4(x1, u1); CVT4(x2, u2); CVT4(x3, u3);
        float p0, p1, p2, p3;
        SCOREX(p0, x0); SCOREX(p1, x1); SCOREX(p2, x2); SCOREX(p3, x3);
        RED16(p0); RED16(p1); RED16(p2); RED16(p3);
        p1 = v1 ? p1 : -1e30f;
        p2 = v2 ? p2 : -1e30f;
        p3 = v3 ? p3 : -1e30f;
        EACC(p0, x0); EACC(p1, x1); EACC(p2, x2); EACC(p3, x3);
    }
    float inv = 1.f / (ssum + 1e-16f);
    float4 bv = *(const float4*)(bias + off);
    float r0 = o.x * inv + bv.x, r1 = o.y * inv + bv.y;
    float r2 = o.z * inv + bv.z, r3 = o.w * inv + bv.w;
    r0 = fmaxf(r0, 0.01f * r0); r1 = fmaxf(r1, 0.01f * r1);
    r2 = fmaxf(r2, 0.01f * r2); r3 = fmaxf(r3, 0.01f * r3);
    ushort4 ov;
    ov.x = f2bf(r0); ov.y = f2bf(r1); ov.z = f2bf(r2); ov.w = f2bf(r3);
    // store in frag layout: row=d, cols off..off+3
    int rowblk = d >> 4, r16d = d & 15;
    int kf = off >> 5, kg2 = (off >> 3) & 3, e0 = off & 7;
    size_t flat = (((size_t)rowblk * 8 + kf) * 64 + kg2 * 16 + r16d) * 8 + e0;
    *(ushort4*)(outb + flat) = ov;
}

// ---------------- fused edge phase, H=1 (no-max) ----------------
__global__ __launch_bounds__(256) void node_attn_h1(
    const unsigned short* __restrict__ xlr,  // [n][128] row-major
    const float* __restrict__ att, const float* __restrict__ bias,
    const int* __restrict__ rowptr, const int* __restrict__ sord, int n,
    float* __restrict__ outf)
{
    int d = (blockIdx.x * blockDim.x + threadIdx.x) >> 6;
    int lane = threadIdx.x & 63;
    if (d >= n) return;
    int sg = lane >> 4, c0 = (lane & 15) * 4;
    ushort4 xru = *(const ushort4*)(xlr + (size_t)d * 128 + 64 + c0);
    CVT4(xrv, xru);
    float4 atv = *(const float4*)(att + c0);
    float4 a6, a4;
    a6.x = atv.x * (0.6f * LOG2E); a6.y = atv.y * (0.6f * LOG2E);
    a6.z = atv.z * (0.6f * LOG2E); a6.w = atv.w * (0.6f * LOG2E);
    a4.x = atv.x * (0.4f * LOG2E); a4.y = atv.y * (0.4f * LOG2E);
    a4.z = atv.z * (0.4f * LOG2E); a4.w = atv.w * (0.4f * LOG2E);
    int beg = rowptr[d], end = rowptr[d + 1];
    float ssum = 0.f;
    float4 o = {0.f, 0.f, 0.f, 0.f};
    for (int i0 = beg; i0 < end; i0 += 8) {
        int ia = i0 + sg, ib = i0 + 4 + sg;
        int va = ia < end, vb = ib < end;
        int sa = sord[va ? ia : beg];
        int sb = sord[vb ? ib : beg];
        ushort4 ua = *(const ushort4*)(xlr + (size_t)sa * 128 + c0);
        ushort4 ub = *(const ushort4*)(xlr + (size_t)sb * 128 + c0);
        CVT4(xa, ua); CVT4(xb, ub);
        float pa, pb;
        SCOREX(pa, xa); SCOREX(pb, xb);
        RED16(pa); RED16(pb);
        pa = va ? pa : -1e30f;
        pb = vb ? pb : -1e30f;
        EACC(pa, xa); EACC(pb, xb);
    }
    // plain-sum merge of the 4 subgroup states
#pragma unroll
    for (int offs = 16; offs <= 32; offs <<= 1) {
        ssum += __shfl_xor(ssum, offs);
        o.x += __shfl_xor(o.x, offs); o.y += __shfl_xor(o.y, offs);
        o.z += __shfl_xor(o.z, offs); o.w += __shfl_xor(o.w, offs);
    }
    if (sg == 0) {
        float inv = 1.f / (ssum + 1e-16f);
        float4 bv = *(const float4*)(bias + c0);
        float4 res;
        res.x = o.x * inv + bv.x; res.y = o.y * inv + bv.y;
        res.z = o.z * inv + bv.z; res.w = o.w * inv + bv.w;
        *(float4*)(outf + (size_t)d * 64 + c0) = res;
    }
}

// fused predict head
__global__ void predict_head(const float* __restrict__ h2,
                             const float* __restrict__ Wp1, const float* __restrict__ bp1,
                             const float* __restrict__ Wp2, const float* __restrict__ bp2,
                             float* __restrict__ logits, int n)
{
    int i = blockIdx.x * blockDim.x + threadIdx.x;
    if (i >= n) return;
    float h[64];
#pragma unroll
    for (int c = 0; c < 64; c++) h[c] = h2[(long long)i * 64 + c];
    float logit = bp2[0];
#pragma unroll
    for (int j = 0; j < 32; j++) {
        float z = bp1[j];
#pragma unroll
        for (int c = 0; c < 64; c++) z += h[c] * Wp1[c * 32 + j];
        z = lrelu(z, 0.01f);
        logit += z * Wp2[j];
    }
    logits[i] = logit;
}

extern "C" void kernel_launch(void* const* d_in, const int* in_sizes, int n_in,
                              void* d_out, int out_size, void* d_ws, size_t ws_size,
                              hipStream_t stream)
{
    const float* x    = (const float*)d_in[0];
    const int*   eidx = (const int*)d_in[1];
    const float* W1l  = (const float*)d_in[2];
    const float* b1l  = (const float*)d_in[3];
    const float* W1r  = (const float*)d_in[4];
    const float* b1r  = (const float*)d_in[5];
    const float* att1 = (const float*)d_in[6];
    const float* bias1= (const float*)d_in[7];
    const float* W2l  = (const float*)d_in[8];
    const float* b2l  = (const float*)d_in[9];
    const float* W2r  = (const float*)d_in[10];
    const float* b2r  = (const float*)d_in[11];
    const float* att2 = (const float*)d_in[12];
    const float* bias2= (const float*)d_in[13];
    const float* Wp1  = (const float*)d_in[14];
    const float* bp1  = (const float*)d_in[15];
    const float* Wp2  = (const float*)d_in[16];
    const float* bp2  = (const float*)d_in[17];

    const int n = in_sizes[0] / 256;  // 50000
    const int E = in_sizes[1] / 2;    // 600000
    const int Etot = E + n;
    const int nb = (n + 1023) / 1024;
    const int nrb = (n + 15) / 16;    // 16-row blocks

    float* out = (float*)d_out;       // [0,n): logits ; [n, n+n*64): h
    unsigned short* ws16 = (unsigned short*)d_ws;

    // workspace layout (shorts)
    unsigned short* xb    = ws16;                         // nrb*4096 (frag; aliased h1b)
    unsigned short* xlr1  = xb + (size_t)nrb * 4096;      // n*512 row-major (aliased xlr2)
    unsigned short* w1t   = xlr1 + (size_t)n * 512;       // 131072 (frag)
    unsigned short* w2t   = w1t + 131072;                 // 32768 (frag)
    int*            rowptr= (int*)(w2t + 32768);          // n+1
    int*            cnt   = rowptr + (n + 1);             // n
    int*            sord  = cnt + n;                      // Etot
    int*            pos   = sord + Etot;                  // Etot
    int*            psum  = pos + Etot;                   // 64
    int*            pofs  = psum + 64;                    // 64
    int*            flagp = pofs + 64;                    // 1
    unsigned short* h1b   = xb;                           // attn1 out (frag), gemm2 in
    unsigned short* xlr2  = xlr1;                         // n*128 row-major
    float*          h2    = out + n;

    detect_i64<<<1, 64, 0, stream>>>((const unsigned int*)eidx, flagp);

    // ---- CSR build (one atomic pass) ----
    hipMemsetAsync(cnt, 0, (size_t)n * sizeof(int), stream);
    hist_dst_pos<<<(Etot + 255) / 256, 256, 0, stream>>>(eidx, flagp, E, n, cnt, pos);
    scan1<<<nb, 1024, 0, stream>>>(cnt, rowptr, psum, n);
    scan2<<<1, 64, 0, stream>>>(psum, pofs, rowptr + n, nb);
    scan3<<<nb, 1024, 0, stream>>>(rowptr, pofs, n);
    scatter_pos<<<(Etot + 255) / 256, 256, 0, stream>>>(eidx, flagp, E, n, rowptr, pos, sord);

    // ---- conversions (frag layouts, single launch) ----
    convert_all<<<(nrb * 512 + 20480 + 255) / 256, 256, 0, stream>>>(
        x, W1l, W1r, W2l, W2r, xb, w1t, w2t, n, nrb);

    // ---- layer 1 projection: [n,256] @ [512,256]^T, wave = 4rb x 8cb ----
    {
        dim3 grid((nrb + 7) / 8, 2);
        gemm_frag<512, 256, 4, 8><<<grid, 256, 0, stream>>>(xb, w1t, b1l, b1r, 256, xlr1, n, nrb);
    }

    // ---- layer 1 edge phase ----
    node_attn_h4<<<(n + 3) / 4, 256, 0, stream>>>(xlr1, att1, bias1, rowptr, sord, n, h1b);

    // ---- layer 2 projection: [n,256] @ [128,256]^T, wave = 2rb x 4cb ----
    {
        dim3 grid((nrb + 3) / 4, 1);
        gemm_frag<128, 256, 2, 4><<<grid, 256, 0, stream>>>(h1b, w2t, b2l, b2r, 64, xlr2, n, nrb);
    }

    // ---- layer 2 edge phase ----
    node_attn_h1<<<(n + 3) / 4, 256, 0, stream>>>(xlr2, att2, bias2, rowptr, sord, n, h2);

    // ---- predict head ----
    predict_head<<<(n + 255) / 256, 256, 0, stream>>>(h2, Wp1, bp1, Wp2, bp2, out, n);
}

// Round 13
// 226.566 us; speedup vs baseline: 1.8056x; 1.0999x over previous
//
#include <hip/hip_runtime.h>

typedef __attribute__((ext_vector_type(8))) __bf16 bf16x8;
typedef __attribute__((ext_vector_type(4))) float f32x4;

#define EXP2 __builtin_amdgcn_exp2f
#define LOG2E 1.44269504f
#define MFMA __builtin_amdgcn_mfma_f32_16x16x32_bf16

// async global->LDS 16B per lane: dst wave-uniform, src per-lane (+lane*16B)
#define GLL(srcp, dstp) __builtin_amdgcn_global_load_lds( \
    (const __attribute__((address_space(1))) void*)(srcp), \
    (__attribute__((address_space(3))) void*)(dstp), 16, 0, 0)

__device__ __forceinline__ float lrelu(float v, float s) { return v > 0.f ? v : v * s; }

__device__ __forceinline__ unsigned short f2bf(float f) {
    unsigned int u = __float_as_uint(f);
    u += 0x7FFFu + ((u >> 16) & 1u);
    return (unsigned short)(u >> 16);
}
__device__ __forceinline__ float bf2f(unsigned short u) {
    return __uint_as_float((unsigned int)u << 16);
}

__device__ __forceinline__ int ld_idx(const int* p, int e, int is64) {
    return is64 ? (int)(((const long long*)p)[e]) : p[e];
}

__global__ void detect_i64(const unsigned int* idx, int* flag) {
    if (blockIdx.x == 0 && threadIdx.x == 0) {
        int all0 = 1;
        for (int i = 1; i < 256; i += 2) {
            if (idx[i] != 0u) { all0 = 0; break; }
        }
        *flag = all0;
    }
}

// ---------------- fused conversions (fragment-linear layouts) ----------------
// frag chunk t = ((blk16*KF + kf)*64 + kg*16 + r16) holds 8 bf16 =
// elems [blk16*16 + r16][kf*32 + kg*8 .. +8]  (KF = 8 for K=256)
__global__ void convert_all(const float* __restrict__ x,
                            const float* __restrict__ W1l, const float* __restrict__ W1r,
                            const float* __restrict__ W2l, const float* __restrict__ W2r,
                            unsigned short* __restrict__ xb,
                            unsigned short* __restrict__ w1t, unsigned short* __restrict__ w2t,
                            int n, int nrb)
{
    int t = blockIdx.x * blockDim.x + threadIdx.x;
    int A = nrb * 512;
    if (t < A) {
        int lane = t & 63;
        int kf = (t >> 6) & 7;
        int rowblk = t >> 9;
        int r16 = lane & 15, kg = lane >> 4;
        int row = rowblk * 16 + r16;
        int k0 = kf * 32 + kg * 8;
        ushort4 o0 = {0, 0, 0, 0}, o1 = {0, 0, 0, 0};
        if (row < n) {
            float4 v0 = *(const float4*)(x + (size_t)row * 256 + k0);
            float4 v1 = *(const float4*)(x + (size_t)row * 256 + k0 + 4);
            o0.x = f2bf(v0.x); o0.y = f2bf(v0.y); o0.z = f2bf(v0.z); o0.w = f2bf(v0.w);
            o1.x = f2bf(v1.x); o1.y = f2bf(v1.y); o1.z = f2bf(v1.z); o1.w = f2bf(v1.w);
        }
        *(ushort4*)(xb + (size_t)t * 8) = o0;
        *(ushort4*)(xb + (size_t)t * 8 + 4) = o1;
        return;
    }
    int tw = t - A;
    const float *Wl, *Wr;
    unsigned short* dst;
    int NL, base;
    if (tw < 16384)      { Wl = W1l; Wr = W1r; dst = w1t; NL = 256; base = tw; }
    else if (tw < 20480) { Wl = W2l; Wr = W2r; dst = w2t; NL = 64;  base = tw - 16384; }
    else return;
    int lane = base & 63, kf = (base >> 6) & 7, colblk = base >> 9;
    int r16 = lane & 15, kg = lane >> 4;
    int col = colblk * 16 + r16;
    int k0 = kf * 32 + kg * 8;
    const float* W = (col < NL) ? Wl : Wr;
    int c = (col < NL) ? col : col - NL;
    unsigned short v[8];
#pragma unroll
    for (int e = 0; e < 8; e++) v[e] = f2bf(W[(size_t)(k0 + e) * NL + c]);
    ushort4 o0 = {v[0], v[1], v[2], v[3]}, o1 = {v[4], v[5], v[6], v[7]};
    *(ushort4*)(dst + (size_t)base * 8) = o0;
    *(ushort4*)(dst + (size_t)base * 8 + 4) = o1;
}

// ---------------- LDS-staged double-buffered MFMA GEMM ----------------
// 128x128 tile (8 rowblks x 8 colblks in frag layout), BK=32 (1 kf-chunk).
// Per step: stage next 16x1KB chunks via global_load_lds (async), then
// ds_read current frags + 16 MFMA/wave. 4 waves (2x2), acc[4][4] = 64 AGPR.
template <int KF>
__global__ __launch_bounds__(256) void gemm_lds(
    const unsigned short* __restrict__ A, const unsigned short* __restrict__ Bt,
    const float* __restrict__ biasL, const float* __restrict__ biasR, int NL,
    unsigned short* __restrict__ C, int M, int nrb, int N)
{
    __shared__ unsigned short lds[2][16 * 512];   // 2 x 16KB
    int wid = threadIdx.x >> 6, lane = threadIdx.x & 63;
    int wm = wid >> 1, wn = wid & 1;
    int rb0 = blockIdx.x * 8;
    int cb0 = blockIdx.y * 8;

    // stage chunk set for kf into lds[buf]: chunks 0-7 = A rowblks, 8-15 = B colblks
    auto stage = [&](int buf, int kf) {
#pragma unroll
        for (int i = 0; i < 4; i++) {
            int c = wid * 4 + i;
            const unsigned short* src;
            if (c < 8) {
                int rb = rb0 + c;
                rb = rb < nrb ? rb : nrb - 1;
                src = A + ((size_t)rb * KF + kf) * 512;
            } else {
                src = Bt + ((size_t)(cb0 + c - 8) * KF + kf) * 512;
            }
            GLL(src + lane * 8, &lds[buf][c * 512]);
        }
    };

    f32x4 acc[4][4] = {};
    stage(0, 0);
    __syncthreads();
    int cur = 0;
    for (int kf = 0; kf < KF; kf++) {
        if (kf + 1 < KF) stage(cur ^ 1, kf + 1);
        bf16x8 a[4], b[4];
#pragma unroll
        for (int r = 0; r < 4; r++)
            a[r] = *(const bf16x8*)&lds[cur][(wm * 4 + r) * 512 + lane * 8];
#pragma unroll
        for (int j = 0; j < 4; j++)
            b[j] = *(const bf16x8*)&lds[cur][(8 + wn * 4 + j) * 512 + lane * 8];
#pragma unroll
        for (int j = 0; j < 4; j++)
#pragma unroll
            for (int r = 0; r < 4; r++)
                acc[r][j] = MFMA(a[r], b[j], acc[r][j], 0, 0, 0);
        __syncthreads();   // drains staging vmcnt + protects buffer swap
        cur ^= 1;
    }

    int ccol = lane & 15, crow = (lane >> 4) * 4;
#pragma unroll
    for (int r = 0; r < 4; r++) {
#pragma unroll
        for (int j = 0; j < 4; j++) {
            int col = (cb0 + wn * 4 + j) * 16 + ccol;
            float bv = (col < NL) ? biasL[col] : biasR[col - NL];
#pragma unroll
            for (int q = 0; q < 4; q++) {
                int row = (rb0 + wm * 4 + r) * 16 + crow + q;
                if (row < M) C[(size_t)row * N + col] = f2bf(acc[r][j][q] + bv);
            }
        }
    }
}

// ---------------- CSR build (single atomic pass) ----------------
__global__ void hist_dst_pos(const int* __restrict__ eidx, const int* __restrict__ flagp,
                             int E, int n, int* __restrict__ cnt, int* __restrict__ pos)
{
    int t = blockIdx.x * blockDim.x + threadIdx.x;
    if (t >= E + n) return;
    int is64 = *flagp;
    int d = (t < E) ? ld_idx(eidx, E + t, is64) : (t - E);
    pos[t] = atomicAdd(&cnt[d], 1);
}

__global__ __launch_bounds__(1024) void scan1(const int* __restrict__ cnt,
                                              int* __restrict__ rowptr, int* __restrict__ psum, int n)
{
    __shared__ int wsum[16];
    int tid = threadIdx.x, lane = tid & 63, w = tid >> 6;
    int gid = blockIdx.x * 1024 + tid;
    int v = (gid < n) ? cnt[gid] : 0;
    int sc = v;
#pragma unroll
    for (int o = 1; o < 64; o <<= 1) { int t2 = __shfl_up(sc, o); if (lane >= o) sc += t2; }
    if (lane == 63) wsum[w] = sc;
    __syncthreads();
    if (tid < 16) {
        int t2 = wsum[tid];
#pragma unroll
        for (int o = 1; o < 16; o <<= 1) { int u = __shfl_up(t2, o); if (tid >= o) t2 += u; }
        wsum[tid] = t2;
    }
    __syncthreads();
    int wofs = w ? wsum[w - 1] : 0;
    if (gid < n) rowptr[gid] = wofs + sc - v;
    if (tid == 1023) psum[blockIdx.x] = wsum[15];
}

__global__ void scan2(const int* __restrict__ psum, int* __restrict__ pofs,
                      int* __restrict__ rowptr_n, int nb)
{
    int lane = threadIdx.x;
    int v = (lane < nb) ? psum[lane] : 0;
    int sc = v;
#pragma unroll
    for (int o = 1; o < 64; o <<= 1) { int t = __shfl_up(sc, o); if (lane >= o) sc += t; }
    if (lane < nb) pofs[lane] = sc - v;
    if (lane == 63) *rowptr_n = sc;
}

__global__ __launch_bounds__(1024) void scan3(int* __restrict__ rowptr,
                                              const int* __restrict__ pofs, int n)
{
    int gid = blockIdx.x * 1024 + threadIdx.x;
    if (gid < n) rowptr[gid] += pofs[blockIdx.x];
}

__global__ void scatter_pos(const int* __restrict__ eidx, const int* __restrict__ flagp,
                            int E, int n, const int* __restrict__ rowptr,
                            const int* __restrict__ pos, int* __restrict__ sord)
{
    int t = blockIdx.x * blockDim.x + threadIdx.x;
    if (t >= E + n) return;
    int is64 = *flagp;
    int s, d;
    if (t < E) { s = ld_idx(eidx, t, is64); d = ld_idx(eidx, E + t, is64); }
    else { s = t - E; d = s; }
    sord[rowptr[d] + pos[t]] = s;
}

// ---------------- fused edge phase (no-max softmax: shift-invariant, scores |p|<~20) ----------------
// score via lrelu(t)*att = t*(0.6*att) + |t|*(0.4*att), LOG2E folded into att
#define SCOREX(p, xv) { float t_; p = 0.f;                              \
    t_ = xv.x + xrv.x; p = fmaf(t_, a6.x, p); p = fmaf(fabsf(t_), a4.x, p); \
    t_ = xv.y + xrv.y; p = fmaf(t_, a6.y, p); p = fmaf(fabsf(t_), a4.y, p); \
    t_ = xv.z + xrv.z; p = fmaf(t_, a6.z, p); p = fmaf(fabsf(t_), a4.z, p); \
    t_ = xv.w + xrv.w; p = fmaf(t_, a6.w, p); p = fmaf(fabsf(t_), a4.w, p); }

#define RED16(p) { p += __shfl_xor(p, 1); p += __shfl_xor(p, 2);    \
                   p += __shfl_xor(p, 4); p += __shfl_xor(p, 8); }

#define EACC(v, xv) { float ev = EXP2(v); ssum += ev;                \
    o.x = fmaf(ev, xv.x, o.x); o.y = fmaf(ev, xv.y, o.y);            \
    o.z = fmaf(ev, xv.z, o.z); o.w = fmaf(ev, xv.w, o.w); }

#define CVT4(f, u) float4 f = { bf2f(u.x), bf2f(u.y), bf2f(u.z), bf2f(u.w) };

__global__ __launch_bounds__(256) void node_attn_h4(
    const unsigned short* __restrict__ xlr,  // [n][512] row-major
    const float* __restrict__ att, const float* __restrict__ bias,
    const int* __restrict__ rowptr, const int* __restrict__ sord, int n,
    unsigned short* __restrict__ outb)       // frag layout (feeds gemm2)
{
    int d = (blockIdx.x * blockDim.x + threadIdx.x) >> 6;
    int lane = threadIdx.x & 63;
    if (d >= n) return;
    int off = (lane >> 4) * 64 + (lane & 15) * 4;  // h*64 + c0
    ushort4 xru = *(const ushort4*)(xlr + (size_t)d * 512 + 256 + off);
    CVT4(xrv, xru);
    float4 atv = *(const float4*)(att + off);
    float4 a6, a4;
    a6.x = atv.x * (0.6f * LOG2E); a6.y = atv.y * (0.6f * LOG2E);
    a6.z = atv.z * (0.6f * LOG2E); a6.w = atv.w * (0.6f * LOG2E);
    a4.x = atv.x * (0.4f * LOG2E); a4.y = atv.y * (0.4f * LOG2E);
    a4.z = atv.z * (0.4f * LOG2E); a4.w = atv.w * (0.4f * LOG2E);
    int beg = rowptr[d], end = rowptr[d + 1];
    float ssum = 0.f;
    float4 o = {0.f, 0.f, 0.f, 0.f};
    for (int i = beg; i < end; i += 4) {
        int i1 = i + 1, i2 = i + 2, i3 = i + 3;
        int v1 = i1 < end, v2 = i2 < end, v3 = i3 < end;
        int s0 = sord[i];
        int s1 = sord[v1 ? i1 : i];
        int s2 = sord[v2 ? i2 : i];
        int s3 = sord[v3 ? i3 : i];
        ushort4 u0 = *(const ushort4*)(xlr + (size_t)s0 * 512 + off);
        ushort4 u1 = *(const ushort4*)(xlr + (size_t)s1 * 512 + off);
        ushort4 u2 = *(const ushort4*)(xlr + (size_t)s2 * 512 + off);
        ushort4 u3 = *(const ushort4*)(xlr + (size_t)s3 * 512 + off);
        CVT4(x0, u0); CVT4(x1, u1); CVT4(x2, u2); CVT4(x3, u3);
        float p0, p1, p2, p3;
        SCOREX(p0, x0); SCOREX(p1, x1); SCOREX(p2, x2); SCOREX(p3, x3);
        RED16(p0); RED16(p1); RED16(p2); RED16(p3);
        p1 = v1 ? p1 : -1e30f;
        p2 = v2 ? p2 : -1e30f;
        p3 = v3 ? p3 : -1e30f;
        EACC(p0, x0); EACC(p1, x1); EACC(p2, x2); EACC(p3, x3);
    }
    float inv = 1.f / (ssum + 1e-16f);
    float4 bv = *(const float4*)(bias + off);
    float r0 = o.x * inv + bv.x, r1 = o.y * inv + bv.y;
    float r2 = o.z * inv + bv.z, r3 = o.w * inv + bv.w;
    r0 = fmaxf(r0, 0.01f * r0); r1 = fmaxf(r1, 0.01f * r1);
    r2 = fmaxf(r2, 0.01f * r2); r3 = fmaxf(r3, 0.01f * r3);
    ushort4 ov;
    ov.x = f2bf(r0); ov.y = f2bf(r1); ov.z = f2bf(r2); ov.w = f2bf(r3);
    // store in frag layout: row=d, cols off..off+3
    int rowblk = d >> 4, r16d = d & 15;
    int kf = off >> 5, kg2 = (off >> 3) & 3, e0 = off & 7;
    size_t flat = (((size_t)rowblk * 8 + kf) * 64 + kg2 * 16 + r16d) * 8 + e0;
    *(ushort4*)(outb + flat) = ov;
}

// ---------------- fused edge phase, H=1 (no-max) ----------------
__global__ __launch_bounds__(256) void node_attn_h1(
    const unsigned short* __restrict__ xlr,  // [n][128] row-major
    const float* __restrict__ att, const float* __restrict__ bias,
    const int* __restrict__ rowptr, const int* __restrict__ sord, int n,
    float* __restrict__ outf)
{
    int d = (blockIdx.x * blockDim.x + threadIdx.x) >> 6;
    int lane = threadIdx.x & 63;
    if (d >= n) return;
    int sg = lane >> 4, c0 = (lane & 15) * 4;
    ushort4 xru = *(const ushort4*)(xlr + (size_t)d * 128 + 64 + c0);
    CVT4(xrv, xru);
    float4 atv = *(const float4*)(att + c0);
    float4 a6, a4;
    a6.x = atv.x * (0.6f * LOG2E); a6.y = atv.y * (0.6f * LOG2E);
    a6.z = atv.z * (0.6f * LOG2E); a6.w = atv.w * (0.6f * LOG2E);
    a4.x = atv.x * (0.4f * LOG2E); a4.y = atv.y * (0.4f * LOG2E);
    a4.z = atv.z * (0.4f * LOG2E); a4.w = atv.w * (0.4f * LOG2E);
    int beg = rowptr[d], end = rowptr[d + 1];
    float ssum = 0.f;
    float4 o = {0.f, 0.f, 0.f, 0.f};
    for (int i0 = beg; i0 < end; i0 += 8) {
        int ia = i0 + sg, ib = i0 + 4 + sg;
        int va = ia < end, vb = ib < end;
        int sa = sord[va ? ia : beg];
        int sb = sord[vb ? ib : beg];
        ushort4 ua = *(const ushort4*)(xlr + (size_t)sa * 128 + c0);
        ushort4 ub = *(const ushort4*)(xlr + (size_t)sb * 128 + c0);
        CVT4(xa, ua); CVT4(xb, ub);
        float pa, pb;
        SCOREX(pa, xa); SCOREX(pb, xb);
        RED16(pa); RED16(pb);
        pa = va ? pa : -1e30f;
        pb = vb ? pb : -1e30f;
        EACC(pa, xa); EACC(pb, xb);
    }
    // plain-sum merge of the 4 subgroup states
#pragma unroll
    for (int offs = 16; offs <= 32; offs <<= 1) {
        ssum += __shfl_xor(ssum, offs);
        o.x += __shfl_xor(o.x, offs); o.y += __shfl_xor(o.y, offs);
        o.z += __shfl_xor(o.z, offs); o.w += __shfl_xor(o.w, offs);
    }
    if (sg == 0) {
        float inv = 1.f / (ssum + 1e-16f);
        float4 bv = *(const float4*)(bias + c0);
        float4 res;
        res.x = o.x * inv + bv.x; res.y = o.y * inv + bv.y;
        res.z = o.z * inv + bv.z; res.w = o.w * inv + bv.w;
        *(float4*)(outf + (size_t)d * 64 + c0) = res;
    }
}

// fused predict head
__global__ void predict_head(const float* __restrict__ h2,
                             const float* __restrict__ Wp1, const float* __restrict__ bp1,
                             const float* __restrict__ Wp2, const float* __restrict__ bp2,
                             float* __restrict__ logits, int n)
{
    int i = blockIdx.x * blockDim.x + threadIdx.x;
    if (i >= n) return;
    float h[64];
#pragma unroll
    for (int c = 0; c < 64; c++) h[c] = h2[(long long)i * 64 + c];
    float logit = bp2[0];
#pragma unroll
    for (int j = 0; j < 32; j++) {
        float z = bp1[j];
#pragma unroll
        for (int c = 0; c < 64; c++) z += h[c] * Wp1[c * 32 + j];
        z = lrelu(z, 0.01f);
        logit += z * Wp2[j];
    }
    logits[i] = logit;
}

extern "C" void kernel_launch(void* const* d_in, const int* in_sizes, int n_in,
                              void* d_out, int out_size, void* d_ws, size_t ws_size,
                              hipStream_t stream)
{
    const float* x    = (const float*)d_in[0];
    const int*   eidx = (const int*)d_in[1];
    const float* W1l  = (const float*)d_in[2];
    const float* b1l  = (const float*)d_in[3];
    const float* W1r  = (const float*)d_in[4];
    const float* b1r  = (const float*)d_in[5];
    const float* att1 = (const float*)d_in[6];
    const float* bias1= (const float*)d_in[7];
    const float* W2l  = (const float*)d_in[8];
    const float* b2l  = (const float*)d_in[9];
    const float* W2r  = (const float*)d_in[10];
    const float* b2r  = (const float*)d_in[11];
    const float* att2 = (const float*)d_in[12];
    const float* bias2= (const float*)d_in[13];
    const float* Wp1  = (const float*)d_in[14];
    const float* bp1  = (const float*)d_in[15];
    const float* Wp2  = (const float*)d_in[16];
    const float* bp2  = (const float*)d_in[17];

    const int n = in_sizes[0] / 256;  // 50000
    const int E = in_sizes[1] / 2;    // 600000
    const int Etot = E + n;
    const int nb = (n + 1023) / 1024;
    const int nrb = (n + 15) / 16;    // 16-row blocks

    float* out = (float*)d_out;       // [0,n): logits ; [n, n+n*64): h
    unsigned short* ws16 = (unsigned short*)d_ws;

    // workspace layout (shorts)
    unsigned short* xb    = ws16;                         // nrb*4096 (frag; aliased h1b)
    unsigned short* xlr1  = xb + (size_t)nrb * 4096;      // n*512 row-major (aliased xlr2)
    unsigned short* w1t   = xlr1 + (size_t)n * 512;       // 131072 (frag)
    unsigned short* w2t   = w1t + 131072;                 // 32768 (frag)
    int*            rowptr= (int*)(w2t + 32768);          // n+1
    int*            cnt   = rowptr + (n + 1);             // n
    int*            sord  = cnt + n;                      // Etot
    int*            pos   = sord + Etot;                  // Etot
    int*            psum  = pos + Etot;                   // 64
    int*            pofs  = psum + 64;                    // 64
    int*            flagp = pofs + 64;                    // 1
    unsigned short* h1b   = xb;                           // attn1 out (frag), gemm2 in
    unsigned short* xlr2  = xlr1;                         // n*128 row-major
    float*          h2    = out + n;

    detect_i64<<<1, 64, 0, stream>>>((const unsigned int*)eidx, flagp);

    // ---- CSR build (one atomic pass) ----
    hipMemsetAsync(cnt, 0, (size_t)n * sizeof(int), stream);
    hist_dst_pos<<<(Etot + 255) / 256, 256, 0, stream>>>(eidx, flagp, E, n, cnt, pos);
    scan1<<<nb, 1024, 0, stream>>>(cnt, rowptr, psum, n);
    scan2<<<1, 64, 0, stream>>>(psum, pofs, rowptr + n, nb);
    scan3<<<nb, 1024, 0, stream>>>(rowptr, pofs, n);
    scatter_pos<<<(Etot + 255) / 256, 256, 0, stream>>>(eidx, flagp, E, n, rowptr, pos, sord);

    // ---- conversions (frag layouts, single launch) ----
    convert_all<<<(nrb * 512 + 20480 + 255) / 256, 256, 0, stream>>>(
        x, W1l, W1r, W2l, W2r, xb, w1t, w2t, n, nrb);

    // ---- layer 1 projection: [n,256] @ [512,256]^T, LDS-staged 128x128 tiles ----
    {
        dim3 grid((nrb + 7) / 8, 4);
        gemm_lds<8><<<grid, 256, 0, stream>>>(xb, w1t, b1l, b1r, 256, xlr1, n, nrb, 512);
    }

    // ---- layer 1 edge phase ----
    node_attn_h4<<<(n + 3) / 4, 256, 0, stream>>>(xlr1, att1, bias1, rowptr, sord, n, h1b);

    // ---- layer 2 projection: [n,256] @ [128,256]^T ----
    {
        dim3 grid((nrb + 7) / 8, 1);
        gemm_lds<8><<<grid, 256, 0, stream>>>(h1b, w2t, b2l, b2r, 64, xlr2, n, nrb, 128);
    }

    // ---- layer 2 edge phase ----
    node_attn_h1<<<(n + 3) / 4, 256, 0, stream>>>(xlr2, att2, bias2, rowptr, sord, n, h2);

    // ---- predict head ----
    predict_head<<<(n + 255) / 256, 256, 0, stream>>>(h2, Wp1, bp1, Wp2, bp2, out, n);
}